// Round 6
// baseline (4269.531 us; speedup 1.0000x reference)
//
#include <hip/hip_runtime.h>
#include <math.h>

typedef short s8v __attribute__((ext_vector_type(8)));
typedef short s4v __attribute__((ext_vector_type(4)));
typedef float f4v __attribute__((ext_vector_type(4)));
typedef float f16f __attribute__((ext_vector_type(16)));

__device__ __forceinline__ float sigf(float x) { return 1.f / (1.f + expf(-x)); }
__device__ __forceinline__ float b2f(short v) {
  return __uint_as_float(((unsigned)(unsigned short)v) << 16);
}

#define SCALE_CLAMP 4.135166556742356f
#define IMG_SIZE 800.f
#define PLANE 14482432ull   // shorts per activation plane: sumPHW(14143)*4*256

// 3-way bf16 split (round-to-nearest): x ~= h + m + l, err ~2^-27 |x|
__device__ __forceinline__ void split3(float x, short& h, short& m, short& l) {
  unsigned u = __float_as_uint(x);
  unsigned hb = (u + 0x7FFFu + ((u >> 16) & 1u)) >> 16;
  float hf = __uint_as_float(hb << 16);
  float d1 = x - hf;
  unsigned u1 = __float_as_uint(d1);
  unsigned mb = (u1 + 0x7FFFu + ((u1 >> 16) & 1u)) >> 16;
  float mf = __uint_as_float(mb << 16);
  float d2 = d1 - mf;
  unsigned u2 = __float_as_uint(d2);
  unsigned lb = (u2 + 0x7FFFu + ((u2 >> 16) & 1u)) >> 16;
  h = (short)hb; m = (short)mb; l = (short)lb;
}

struct Geo {
  int tp[6];                 // conv tile prefix per level
  int TXa[5];
  int Ha[5], Wa[5], PWa[5], PHWa[5];
  int phwOff[5];             // PHW prefix
  int hwOff[5];              // HW prefix
  int pb[6];                 // ceil(HW/64) prefix  (prep + cls head)
  int bb[6];                 // ceil(HW/256) prefix (box head)
};

// ==================== weight split+transpose (32x32x16 B-frag layout) ====================
// out (bf16 shorts): [layer8][plane3][ (tap*8+cc)*2+ks ][ko 256][half 2][e 8]
// plane stride 589824, layer stride 1769472. ci = cc*32 + ks*16 + half*8 + e.
__global__ __launch_bounds__(256) void wtrans_k(const float* __restrict__ cls_tw,
                                                const float* __restrict__ bbox_tw,
                                                short* __restrict__ wt)
{
  const int total = 589824; // units of s8v: 8 layer * 9 tap * 8 cc * 2 ks * 256 ko * 2 half
  for (int u = blockIdx.x * 256 + threadIdx.x; u < total; u += gridDim.x * 256) {
    int layer = u / 73728;
    int r = u - layer * 73728;
    int tap = r / 8192;  r -= tap * 8192;
    int cc  = r / 1024;  r -= cc * 1024;
    int ks  = r / 512;   r -= ks * 512;
    int ko  = r >> 1;
    int half = r & 1;
    int cibase = cc * 32 + ks * 16 + half * 8;
    const float* src = (layer < 4) ? (cls_tw + (size_t)layer * 589824)
                                   : (bbox_tw + (size_t)(layer - 4) * 589824);
    s8v hv, mv, lv;
#pragma unroll
    for (int e = 0; e < 8; ++e) {
      float x = src[(size_t)ko * 2304 + (size_t)(cibase + e) * 9 + tap];
      short h, m, l; split3(x, h, m, l);
      hv[e] = h; mv[e] = m; lv[e] = l;
    }
    size_t dbase = (size_t)layer * 1769472 +
                   (((size_t)(tap * 8 + cc) * 2 + ks) * 4096) + (size_t)ko * 16 + half * 8;
    *(s8v*)(wt + dbase) = hv;
    *(s8v*)(wt + dbase + 589824) = mv;
    *(s8v*)(wt + dbase + 2 * 589824) = lv;
  }
}

// ==================== NCHW fp32 -> padded split-plane bf16x3 (all levels) ====================
__global__ __launch_bounds__(256) void prep_all_k(const float* __restrict__ p3, const float* __restrict__ p4,
                                                  const float* __restrict__ p5, const float* __restrict__ p6,
                                                  const float* __restrict__ p7,
                                                  short* __restrict__ out, Geo g)
{
  __shared__ float tl[64][260];
  int bx = blockIdx.x, t = threadIdx.x, n = blockIdx.y;
  int l = 0; while (l < 4 && bx >= g.pb[l + 1]) ++l;
  const float* in = (l == 0) ? p3 : (l == 1) ? p4 : (l == 2) ? p5 : (l == 3) ? p6 : p7;
  int H = g.Ha[l], W = g.Wa[l], PW = g.PWa[l], PHW = g.PHWa[l], HW = H * W;
  int P0 = (bx - g.pb[l]) * 64;
  const float* inN = in + (size_t)n * HW * 256;
  int sub = t >> 6, pl = t & 63;
  int pos = P0 + pl;
  for (int i = 0; i < 64; ++i) {
    int ci = i * 4 + sub;
    tl[pl][ci] = (pos < HW) ? inN[(size_t)ci * HW + pos] : 0.f;
  }
  __syncthreads();
  int pl2 = t >> 2, cq = (t & 3) * 64;
  int pos2 = P0 + pl2;
  if (pos2 < HW) {
    int y = pos2 / W, x = pos2 - y * W;
    size_t oo = ((size_t)g.phwOff[l] * 4 + (size_t)n * PHW + (size_t)(y + 1) * PW + (x + 1)) * 256 + cq;
#pragma unroll
    for (int grp = 0; grp < 8; ++grp) {
      s8v hv, mv, lv;
#pragma unroll
      for (int e = 0; e < 8; ++e) {
        short h, m, lo; split3(tl[pl2][cq + grp * 8 + e], h, m, lo);
        hv[e] = h; mv[e] = m; lv[e] = lo;
      }
      *(s8v*)(out + oo + grp * 8) = hv;
      *(s8v*)(out + PLANE + oo + grp * 8) = mv;
      *(s8v*)(out + 2 * PLANE + oo + grp * 8) = lv;
    }
  }
}

// ==================== MFMA conv 3x3 + bias + relu (32x32x16, split-plane in/out) ====================
// Block: 8x16 pos x 128 ko; 4 waves: wm = pos 8-col half, wn = 64-ko half.
// Per wave: 2x2 blocks of 32x32 (M=32 pos as 4x8, N=32 ko), acc 2x2xf32x16.
// Staging: global_load_lds DMA, double-buffered act LDS (73.7 KB, 2 blocks/CU).
// Weights: global(L2)->reg, double-buffered across the unrolled tap loop.
__global__ __launch_bounds__(256, 2) void conv_all_k(const short* __restrict__ in,
                                                     const short* __restrict__ wtL,
                                                     const float* __restrict__ bias,
                                                     short* __restrict__ out, Geo g)
{
  __shared__ short act_s[2 * 3 * 768 * 8];  // [buf][plane][768 pos][8ci] = 73.7 KB

  const int t = threadIdx.x;
  const int lane = t & 63, wave = t >> 6;
  const int wm = wave & 1, wn = wave >> 1;
  const int lk = lane & 31, lh = lane >> 5;
  const int n = blockIdx.z;
  const int ko0 = blockIdx.y * 128;
  int bx = blockIdx.x;
  int l = 0; while (l < 4 && bx >= g.tp[l + 1]) ++l;
  const int H = g.Ha[l], W = g.Wa[l], PW = g.PWa[l], PHW = g.PHWa[l];
  const int lt = bx - g.tp[l];
  const int TX = g.TXa[l];
  const int ty = lt / TX, tx = lt - ty * TX;
  const int R0 = ty * 8, C0 = tx * 16;
  const size_t bi = ((size_t)g.phwOff[l] * 4 + (size_t)n * PHW) * 256;
  const short* inN = in + bi;
  short* outN = out + bi;

  // per-lane weight base (shorts): ko column (lk) + ci half (lh); ni adds 32 ko = 512 shorts
  const short* wlane = wtL + (size_t)(ko0 + wn * 64 + lk) * 16 + lh * 8;

  // per-thread source offsets for the 3 staging sub-iterations (j = t + k*256)
  int soff[3];
#pragma unroll
  for (int k = 0; k < 3; ++k) {
    int j = t + k * 256; if (j > 719) j = 719;
    int qq = j / 180, pos = j - qq * 180;
    int row = pos / 18, col = pos - row * 18;
    int prow = R0 + row; if (prow > H + 1) prow = H + 1;
    int pcol = C0 + col; if (pcol > W + 1) pcol = W + 1;
    soff[k] = (prow * PW + pcol) * 256 + qq * 8;
  }

  f16f acc[2][2];
#pragma unroll
  for (int mi = 0; mi < 2; ++mi)
#pragma unroll
    for (int ni = 0; ni < 2; ++ni)
#pragma unroll
      for (int e = 0; e < 16; ++e) acc[mi][ni][e] = 0.f;

  auto stage = [&](int cc, int buf) {
#pragma unroll
    for (int k = 0; k < 3; ++k)
#pragma unroll
      for (int p = 0; p < 3; ++p) {
        const short* src = inN + (size_t)p * PLANE + (size_t)(soff[k] + cc * 32);
        short* dst = &act_s[(size_t)buf * 18432 + (size_t)p * 6144 + (size_t)(t + k * 256) * 8];
#if __has_builtin(__builtin_amdgcn_global_load_lds)
        __builtin_amdgcn_global_load_lds((const __attribute__((address_space(1))) void*)src,
                                         (__attribute__((address_space(3))) void*)dst, 16, 0, 0);
#else
        *(s8v*)dst = *(const s8v*)src;
#endif
      }
  };

  auto loadB = [&](s8v (&bf)[3][2][2], int cc2, int tap2) {
    const short* base = wlane + ((size_t)(tap2 * 8 + cc2) * 2) * 4096;
#pragma unroll
    for (int p = 0; p < 3; ++p)
#pragma unroll
      for (int ni = 0; ni < 2; ++ni)
#pragma unroll
        for (int ks = 0; ks < 2; ++ks)
          bf[p][ni][ks] = *(const s8v*)(base + (size_t)p * 589824 + (size_t)ks * 4096 + ni * 512);
  };

  auto runTap = [&](const s8v (&bf)[3][2][2], int dy, int dx, int buf) {
    s8v afr[3][2][2];
    const int sbase = buf * 18432;
#pragma unroll
    for (int mi = 0; mi < 2; ++mi)
#pragma unroll
      for (int ks = 0; ks < 2; ++ks) {
        int sl = (ks * 2 + lh) * 180 + (mi * 4 + (lk >> 3) + dy) * 18 + (wm * 8 + (lk & 7) + dx);
        afr[0][mi][ks] = *(const s8v*)&act_s[sbase + sl * 8];
        afr[1][mi][ks] = *(const s8v*)&act_s[sbase + 6144 + sl * 8];
        afr[2][mi][ks] = *(const s8v*)&act_s[sbase + 12288 + sl * 8];
      }
    const int PA[6] = {0, 0, 1, 1, 0, 2};
    const int PB[6] = {0, 1, 0, 1, 2, 0};
#pragma unroll
    for (int pp = 0; pp < 6; ++pp) {
#pragma unroll
      for (int mi = 0; mi < 2; ++mi)
#pragma unroll
        for (int ni = 0; ni < 2; ++ni)
#pragma unroll
          for (int ks = 0; ks < 2; ++ks)
            acc[mi][ni] = __builtin_amdgcn_mfma_f32_32x32x16_bf16(
                afr[PA[pp]][mi][ks], bf[PB[pp]][ni][ks], acc[mi][ni], 0, 0, 0);
    }
  };

  s8v bfrA[3][2][2], bfrB[3][2][2];
  stage(0, 0);
  loadB(bfrA, 0, 0);
  __syncthreads();            // compiler drains vmcnt(0) before s_barrier

  int cur = 0;
  for (int cc = 0; cc < 8; ++cc) {
    if (cc < 7) stage(cc + 1, cur ^ 1);   // DMA hides under the 432 MFMAs below
#pragma unroll
    for (int tap = 0; tap < 9; ++tap) {
      const int dy = tap / 3, dx = tap - dy * 3;
      if (tap < 8) {
        if (tap & 1) loadB(bfrA, cc, tap + 1); else loadB(bfrB, cc, tap + 1);
      } else if (cc < 7) {
        loadB(bfrB, cc + 1, 0);
      }
      if (tap & 1) runTap(bfrB, dy, dx, cur); else runTap(bfrA, dy, dx, cur);
    }
    if (cc < 7) {
#pragma unroll
      for (int p = 0; p < 3; ++p)
#pragma unroll
        for (int ni = 0; ni < 2; ++ni)
#pragma unroll
          for (int ks = 0; ks < 2; ++ks) bfrA[p][ni][ks] = bfrB[p][ni][ks];
    }
    __syncthreads();          // vmcnt drain (DMA landed) + all waves done with act_s[cur]
    cur ^= 1;
  }

  // epilogue: bias + relu + split3, store 3 bf16 planes (masked)
#pragma unroll
  for (int mi = 0; mi < 2; ++mi) {
#pragma unroll
    for (int ni = 0; ni < 2; ++ni) {
      int ko = ko0 + wn * 64 + ni * 32 + lk;
      float bv = bias[ko];
#pragma unroll
      for (int reg = 0; reg < 16; ++reg) {
        int m = (reg & 3) + 8 * (reg >> 2) + 4 * lh;
        int orow = R0 + mi * 4 + (m >> 3);
        int ocol = C0 + wm * 8 + (m & 7);
        if (orow < H && ocol < W) {
          float vv = fmaxf(acc[mi][ni][reg] + bv, 0.f);
          short h, mm, lo; split3(vv, h, mm, lo);
          size_t oo = ((size_t)(orow + 1) * PW + (ocol + 1)) * 256 + ko;
          outN[oo] = h; outN[PLANE + oo] = mm; outN[2 * PLANE + oo] = lo;
        }
      }
    }
  }
}

// ==================== cls head (all levels): 1x1x80 + sigmoid ====================
__global__ __launch_bounds__(256) void cls_head_k(const short* __restrict__ act,
                                                  const float* __restrict__ wcls,
                                                  const float* __restrict__ bcls,
                                                  float* __restrict__ score, Geo g)
{
  __shared__ int   p2s[64];
  __shared__ float as_[64][69];
  __shared__ float ws_[64][84];
  const int t = threadIdx.x;
  const int n = blockIdx.y;
  int bx = blockIdx.x;
  int l = 0; while (l < 4 && bx >= g.pb[l + 1]) ++l;
  const int H = g.Ha[l], W = g.Wa[l], PW = g.PWa[l], PHW = g.PHWa[l], HW = H * W;
  const int P0 = (bx - g.pb[l]) * 64;
  if (t < 64) {
    int p = P0 + t; if (p >= HW) p = HW - 1;
    int y = p / W, x = p - y * W;
    p2s[t] = (y + 1) * PW + x + 1;
  }
  __syncthreads();
  float accv[4][5];
#pragma unroll
  for (int i = 0; i < 4; ++i)
#pragma unroll
    for (int j = 0; j < 5; ++j) accv[i][j] = 0.f;

  const short* actN = act + ((size_t)g.phwOff[l] * 4 + (size_t)n * PHW) * 256;
  const int pg = t >> 4, cg = t & 15;

  for (int c0 = 0; c0 < 256; c0 += 64) {
    for (int i = t; i < 1024; i += 256) {
      int pos = i >> 4, c4 = i & 15;
      size_t o = (size_t)p2s[pos] * 256 + c0 + c4 * 4;
      s4v hv = *(const s4v*)(actN + o);
      s4v mv = *(const s4v*)(actN + PLANE + o);
      s4v lv = *(const s4v*)(actN + 2 * PLANE + o);
      float* dst = &as_[pos][c4 * 4];
#pragma unroll
      for (int e = 0; e < 4; ++e) dst[e] = b2f(hv[e]) + b2f(mv[e]) + b2f(lv[e]);
    }
    for (int i = t; i < 1280; i += 256) {
      int c = i >> 4, c4 = i & 15;
      float4 v = *(const float4*)(wcls + (size_t)c * 256 + c0 + c4 * 4);
      ws_[c4 * 4 + 0][c] = v.x; ws_[c4 * 4 + 1][c] = v.y;
      ws_[c4 * 4 + 2][c] = v.z; ws_[c4 * 4 + 3][c] = v.w;
    }
    __syncthreads();
#pragma unroll 8
    for (int ci = 0; ci < 64; ++ci) {
#pragma unroll
      for (int i = 0; i < 4; ++i) {
        float a = as_[pg * 4 + i][ci];
#pragma unroll
        for (int j = 0; j < 5; ++j)
          accv[i][j] = fmaf(a, ws_[ci][cg * 5 + j], accv[i][j]);
      }
    }
    __syncthreads();
  }
  float* sB = score + ((size_t)g.hwOff[l] * 4 + (size_t)n * HW) * 80;
#pragma unroll
  for (int i = 0; i < 4; ++i) {
    int p = P0 + pg * 4 + i;
    if (p >= HW) continue;
#pragma unroll
    for (int j = 0; j < 5; ++j) {
      int c = cg * 5 + j;
      sB[(size_t)p * 80 + c] = sigf(accv[i][j] + bcls[c]);
    }
  }
}

// ==================== box head (all levels) ====================
__global__ __launch_bounds__(256) void box_head_k(const short* __restrict__ act,
                                                  const float* __restrict__ wbox,
                                                  const float* __restrict__ bb,
                                                  const float* __restrict__ wctr,
                                                  const float* __restrict__ bc,
                                                  const float* __restrict__ scales,
                                                  float* __restrict__ score,
                                                  float* __restrict__ deltas, Geo g)
{
  int n = blockIdx.y;
  int bx = blockIdx.x;
  int l = 0; while (l < 4 && bx >= g.bb[l + 1]) ++l;
  const int H = g.Ha[l], W = g.Wa[l], PW = g.PWa[l], PHW = g.PHWa[l], HW = H * W;
  int p = (bx - g.bb[l]) * 256 + threadIdx.x;
  if (p >= HW) return;
  int y = p / W, x = p - y * W;
  const short* a = act + ((size_t)g.phwOff[l] * 4 + (size_t)n * PHW + (size_t)(y + 1) * PW + x + 1) * 256;
  float d0 = 0, d1 = 0, d2 = 0, d3 = 0, ct = 0;
  for (int gI = 0; gI < 32; ++gI) {
    s8v hv = *(const s8v*)(a + gI * 8);
    s8v mv = *(const s8v*)(a + PLANE + gI * 8);
    s8v lv = *(const s8v*)(a + 2 * PLANE + gI * 8);
#pragma unroll
    for (int e = 0; e < 8; ++e) {
      float av = b2f(hv[e]) + b2f(mv[e]) + b2f(lv[e]);
      int c = gI * 8 + e;
      d0 = fmaf(av, wbox[c], d0);
      d1 = fmaf(av, wbox[256 + c], d1);
      d2 = fmaf(av, wbox[512 + c], d2);
      d3 = fmaf(av, wbox[768 + c], d3);
      ct = fmaf(av, wctr[c], ct);
    }
  }
  float sl = scales[l];
  float* dd = deltas + ((size_t)g.hwOff[l] * 4 + (size_t)n * HW + p) * 4;
  dd[0] = sl * (d0 + bb[0]); dd[1] = sl * (d1 + bb[1]);
  dd[2] = sl * (d2 + bb[2]); dd[3] = sl * (d3 + bb[3]);
  float sct = sigf(ct + bc[0]);
  float* sp = score + ((size_t)g.hwOff[l] * 4 + (size_t)n * HW + p) * 80;
#pragma unroll
  for (int i = 0; i < 20; ++i) {
    float4 v = ((float4*)sp)[i];
    v.x *= sct; v.y *= sct; v.z *= sct; v.w *= sct;
    v.x = (v.x > 0.05f) ? v.x : 0.f;
    v.y = (v.y > 0.05f) ? v.y : 0.f;
    v.z = (v.z > 0.05f) ? v.z : 0.f;
    v.w = (v.w > 0.05f) ? v.w : 0.f;
    ((float4*)sp)[i] = v;
  }
}

// ==================== exact top-1000: 3-pass bit histogram, 20 (level,image) groups ====================
__global__ __launch_bounds__(256) void hist_k(const float* __restrict__ score,
                                              const unsigned* __restrict__ thr,
                                              unsigned* __restrict__ hist, int phase, Geo g)
{
  const int grp = blockIdx.y;
  const int l = grp >> 2, n = grp & 3;
  const int HW = g.Ha[l] * g.Wa[l];
  const int M = HW * 80;
  const float* s = score + ((size_t)g.hwOff[l] * 4 + (size_t)n * HW) * 80;
  unsigned* h = hist + grp * 2048;
  const unsigned* tr = thr + grp * 8;
  __shared__ unsigned lh[2048];
  for (int i = threadIdx.x; i < 2048; i += 256) lh[i] = 0u;
  __syncthreads();
  unsigned B1 = 0, pref = 0;
  if (phase == 1) B1 = tr[0];
  if (phase == 2) pref = (tr[0] << 11) | tr[1];
  for (int idx = blockIdx.x * 256 + threadIdx.x; idx < M; idx += gridDim.x * 256) {
    float v = s[idx];
    if (v > 0.f) {
      unsigned b = __float_as_uint(v);
      if (phase == 0) atomicAdd(&lh[b >> 20], 1u);
      else if (phase == 1) { if ((b >> 20) == B1) atomicAdd(&lh[(b >> 9) & 0x7FFu], 1u); }
      else { if ((b >> 9) == pref) atomicAdd(&lh[b & 0x1FFu], 1u); }
    }
  }
  __syncthreads();
  for (int i = threadIdx.x; i < 2048; i += 256) { unsigned v = lh[i]; if (v) atomicAdd(&h[i], v); }
}

__global__ __launch_bounds__(256) void scan_k(unsigned* __restrict__ hist,
                                              unsigned* __restrict__ thr, int phase)
{
  const int grp = blockIdx.x, t = threadIdx.x;
  unsigned* h  = hist + grp * 2048;
  unsigned* tr = thr + grp * 8;
  const int nb = (phase == 2) ? 512 : 2048;
  const int PB = nb / 256;
  unsigned target = 1000u;
  bool dead = false;
  if (phase >= 1) {
    target = 1000u - tr[2];
    if (tr[0] == 0xFFFFFFFFu) dead = true;
    if (phase == 2 && tr[1] == 0xFFFFFFFFu) dead = true;
  }
  __shared__ unsigned ps[256];
  __shared__ unsigned s_tot;
  const int hi = nb - t * PB;
  unsigned lsum = 0;
  for (int k = 0; k < PB; ++k) lsum += h[hi - 1 - k];
  ps[t] = lsum;
  __syncthreads();
  if (t == 0) {
    unsigned cum = 0;
    for (int i = 0; i < 256; ++i) { unsigned tmp = ps[i]; ps[i] = cum; cum += tmp; }
    s_tot = cum;
  }
  __syncthreads();
  unsigned exc = ps[t], tot = s_tot;
  if (!dead && tot >= target) {
    if (exc < target && exc + lsum >= target) {
      unsigned cum = exc; int bf = 0; unsigned above = 0;
      for (int k = 0; k < PB; ++k) {
        int bidx = hi - 1 - k;
        unsigned c = h[bidx];
        if (cum < target && cum + c >= target) { bf = bidx; above = cum; }
        cum += c;
      }
      if (phase == 0)      { tr[0] = (unsigned)bf; tr[2] = above; }
      else if (phase == 1) { tr[1] = (unsigned)bf; tr[2] = tr[2] + above; }
      else {
        unsigned T = (tr[0] << 20) | (tr[1] << 9) | (unsigned)bf;
        tr[3] = T; tr[4] = target - above;
      }
    }
  } else if (t == 0) {
    if (phase == 0)      { tr[0] = 0xFFFFFFFFu; tr[2] = 0u; }
    else if (phase == 1) { tr[1] = 0xFFFFFFFFu; }
    else                 { tr[3] = 0u; tr[4] = 0u; }
  }
  if (phase == 2 && t == 0) { tr[5] = 0u; tr[6] = 0u; }
}

// ==================== select + decode ====================
__global__ __launch_bounds__(256) void select_k(const float* __restrict__ score,
                                                const float* __restrict__ deltas,
                                                unsigned* __restrict__ thr,
                                                float* __restrict__ cbox, float* __restrict__ csc,
                                                float* __restrict__ ccls, float* __restrict__ cgid,
                                                Geo g)
{
  const int grp = blockIdx.y;
  const int l = grp >> 2, n = grp & 3;
  const int W = g.Wa[l];
  const int HW = g.Ha[l] * W;
  const int M = HW * 80;
  const float stride_ = (float)(8 << l);
  const float* s = score + ((size_t)g.hwOff[l] * 4 + (size_t)n * HW) * 80;
  const float* dBase = deltas + ((size_t)g.hwOff[l] * 4 + (size_t)n * HW) * 4;
  unsigned* tr = thr + grp * 8;
  const unsigned T = tr[3], need = tr[4];
  for (int idx = blockIdx.x * 256 + threadIdx.x; idx < M; idx += gridDim.x * 256) {
    float v = s[idx];
    if (!(v > 0.f)) continue;
    unsigned b = __float_as_uint(v);
    int slot = -1;
    if (b > T) slot = (int)atomicAdd(&tr[5], 1u);
    else if (b == T) {
      unsigned e = atomicAdd(&tr[6], 1u);
      if (e < need) slot = (int)(1000u - need + e);
    }
    if (slot < 0) continue;
    int p = idx / 80, c = idx - p * 80;
    int y = p / W, x = p - y * W;
    const float* d = dBase + (size_t)p * 4;
    float sz  = 8.f * stride_;
    float acx = ((float)x + 0.5f) * stride_;
    float acy = ((float)y + 0.5f) * stride_;
    float dx = d[0] / 10.f, dy = d[1] / 10.f;
    float dw = fminf(d[2] / 5.f, SCALE_CLAMP);
    float dh = fminf(d[3] / 5.f, SCALE_CLAMP);
    float pcx = dx * sz + acx;
    float pcy = dy * sz + acy;
    float pw = expf(dw) * sz;
    float ph = expf(dh) * sz;
    float x1 = pcx - 0.5f * pw, y1_ = pcy - 0.5f * ph;
    float x2 = pcx + 0.5f * pw, y2_ = pcy + 0.5f * ph;
    x1  = fminf(fmaxf(x1, 0.f),  IMG_SIZE);
    y1_ = fminf(fmaxf(y1_, 0.f), IMG_SIZE);
    x2  = fminf(fmaxf(x2, 0.f),  IMG_SIZE);
    y2_ = fminf(fmaxf(y2_, 0.f), IMG_SIZE);
    int cslot = n * 5000 + l * 1000 + slot;
    ((float4*)cbox)[cslot] = make_float4(x1, y1_, x2, y2_);
    csc[cslot]  = sqrtf(v);
    ccls[cslot] = (float)c;
    cgid[cslot] = (float)(((unsigned)l << 20) | (unsigned)idx);
  }
}

// ==================== class-aware greedy NMS ====================
__global__ __launch_bounds__(256) void nms_k(const float* __restrict__ cbox,
                                             const float* __restrict__ csc,
                                             const float* __restrict__ ccls,
                                             const float* __restrict__ cgid,
                                             float* __restrict__ outp)
{
  const int n = blockIdx.x, t = threadIdx.x;
  float sc[20], cl[20], gid[20], bx[20][4];
#pragma unroll
  for (int j = 0; j < 20; ++j) {
    int gidx = j * 256 + t;
    if (gidx < 5000) {
      sc[j] = csc[n * 5000 + gidx];
      float4 b = ((const float4*)cbox)[n * 5000 + gidx];
      bx[j][0] = b.x; bx[j][1] = b.y; bx[j][2] = b.z; bx[j][3] = b.w;
      cl[j]  = ccls[n * 5000 + gidx];
      gid[j] = cgid[n * 5000 + gidx];
    } else { sc[j] = -2.f; bx[j][0] = bx[j][1] = bx[j][2] = bx[j][3] = 0.f; cl[j] = 0.f; gid[j] = 1e9f; }
  }
  __shared__ float rv[4]; __shared__ int rg[4]; __shared__ float rgid[4];
  __shared__ float sbox[4]; __shared__ float scls; __shared__ float sval; __shared__ int sgi;

  for (int it = 0; it < 100; ++it) {
    float bv = -3.f; int bg = 0; float bgid = 2e9f;
#pragma unroll
    for (int j = 0; j < 20; ++j) {
      bool better = (sc[j] > bv) || (sc[j] == bv && gid[j] < bgid);
      if (better) { bv = sc[j]; bg = j * 256 + t; bgid = gid[j]; }
    }
    for (int off = 32; off; off >>= 1) {
      float ov = __shfl_xor(bv, off);
      int   og = __shfl_xor(bg, off);
      float oi = __shfl_xor(bgid, off);
      bool better = (ov > bv) || (ov == bv && oi < bgid);
      if (better) { bv = ov; bg = og; bgid = oi; }
    }
    int wid = t >> 6;
    if ((t & 63) == 0) { rv[wid] = bv; rg[wid] = bg; rgid[wid] = bgid; }
    __syncthreads();
    if (t == 0) {
      float fv = rv[0]; int fg = rg[0]; float fi = rgid[0];
      for (int w = 1; w < 4; ++w) {
        bool better = (rv[w] > fv) || (rv[w] == fv && rgid[w] < fi);
        if (better) { fv = rv[w]; fg = rg[w]; fi = rgid[w]; }
      }
      sval = fv; sgi = fg;
    }
    __syncthreads();
    float best_v = sval; int best_g = sgi;
    if (t == (best_g & 255)) {
      int j = best_g >> 8;
      sbox[0] = bx[j][0]; sbox[1] = bx[j][1]; sbox[2] = bx[j][2]; sbox[3] = bx[j][3];
      scls = cl[j];
    }
    __syncthreads();
    bool valid = best_v > 0.f;
    if (t == 0) {
      int base = n * 100 + it;
      outp[base * 4 + 0] = valid ? sbox[0] : 0.f;
      outp[base * 4 + 1] = valid ? sbox[1] : 0.f;
      outp[base * 4 + 2] = valid ? sbox[2] : 0.f;
      outp[base * 4 + 3] = valid ? sbox[3] : 0.f;
      outp[1600 + base] = valid ? best_v : 0.f;
      outp[2000 + base] = valid ? scls : -1.f;
    }
    float off_ = scls * (2.f * IMG_SIZE);
    float e0 = sbox[0] + off_, e1 = sbox[1] + off_, e2 = sbox[2] + off_, e3 = sbox[3] + off_;
    float a1 = (e2 - e0) * (e3 - e1);
#pragma unroll
    for (int j = 0; j < 20; ++j) {
      float o_ = cl[j] * (2.f * IMG_SIZE);
      float f0 = bx[j][0] + o_, f1 = bx[j][1] + o_, f2 = bx[j][2] + o_, f3 = bx[j][3] + o_;
      float xx1 = fmaxf(e0, f0), yy1 = fmaxf(e1, f1);
      float xx2 = fminf(e2, f2), yy2 = fminf(e3, f3);
      float inter = fmaxf(xx2 - xx1, 0.f) * fmaxf(yy2 - yy1, 0.f);
      float a2 = (f2 - f0) * (f3 - f1);
      float iou = inter / (a1 + a2 - inter + 1e-9f);
      if (iou > 0.6f) sc[j] = -1.f;
      if ((j * 256 + t) == best_g) sc[j] = -1.f;
    }
    __syncthreads();
  }
}

// ==================== host ====================
extern "C" void kernel_launch(void* const* d_in, const int* in_sizes, int n_in,
                              void* d_out, int out_size, void* d_ws, size_t ws_size,
                              hipStream_t stream)
{
  (void)in_sizes; (void)n_in; (void)out_size; (void)ws_size;
  const float* p3 = (const float*)d_in[0];
  const float* p4 = (const float*)d_in[1];
  const float* p5 = (const float*)d_in[2];
  const float* p6 = (const float*)d_in[3];
  const float* p7 = (const float*)d_in[4];
  const float* cls_tw  = (const float*)d_in[5];
  const float* cls_tb  = (const float*)d_in[6];
  const float* bbox_tw = (const float*)d_in[7];
  const float* bbox_tb = (const float*)d_in[8];
  const float* wcls    = (const float*)d_in[9];
  const float* bcls    = (const float*)d_in[10];
  const float* wbox    = (const float*)d_in[11];
  const float* bbox_b  = (const float*)d_in[12];
  const float* wctr    = (const float*)d_in[13];
  const float* bctr    = (const float*)d_in[14];
  const float* scales  = (const float*)d_in[15];
  float* out = (float*)d_out;

  // geometry
  Geo G;
  const int Hs[5] = {100, 50, 25, 13, 7};
  {
    int tpre = 0, ppre = 0, bpre = 0, phw = 0, hw = 0;
    for (int l = 0; l < 5; ++l) {
      int H = Hs[l], W = Hs[l];
      G.Ha[l] = H; G.Wa[l] = W; G.PWa[l] = W + 2; G.PHWa[l] = (H + 2) * (W + 2);
      G.TXa[l] = (W + 15) / 16;
      int TY = (H + 7) / 8;
      G.tp[l] = tpre;  tpre += G.TXa[l] * TY;
      G.pb[l] = ppre;  ppre += (H * W + 63) / 64;
      G.bb[l] = bpre;  bpre += (H * W + 255) / 256;
      G.phwOff[l] = phw; phw += G.PHWa[l];
      G.hwOff[l]  = hw;  hw  += H * W;
    }
    G.tp[5] = tpre; G.pb[5] = ppre; G.bb[5] = bpre;
  }
  const int nTiles = G.tp[5];   // 130
  const int nPrep  = G.pb[5];   // 211
  const int nBoxB  = G.bb[5];   // 55
  const int sumHW = 13343;

  char* ws = (char*)d_ws;
  size_t off = 0;
  auto alloc = [&](size_t bytes) -> void* {
    off = (off + 255) & ~(size_t)255;
    void* p = ws + off; off += bytes; return p;
  };
  const size_t bufBytes = 3ull * PLANE * 2;   // 3 bf16 planes = 86.9 MB
  short* bufA = (short*)alloc(bufBytes);
  short* bufB = (short*)alloc(bufBytes);
  short* wt   = (short*)alloc((size_t)8 * 3 * 589824 * 2);
  float* score  = (float*)alloc((size_t)sumHW * 4 * 80 * 4);
  float* deltas = (float*)alloc((size_t)sumHW * 4 * 4 * 4);
  float* cbox   = (float*)alloc(4ull * 5000 * 4 * 4);
  float* csc    = (float*)alloc(4ull * 5000 * 4);
  float* ccls   = (float*)alloc(4ull * 5000 * 4);
  float* cgid   = (float*)alloc(4ull * 5000 * 4);
  unsigned* hist = (unsigned*)alloc(20ull * 2048 * 4);
  unsigned* thr  = (unsigned*)alloc(20ull * 8 * 4);

  hipMemsetAsync(bufA, 0, bufBytes, stream);   // zero borders for all planes
  hipMemsetAsync(bufB, 0, bufBytes, stream);
  hipMemsetAsync(cbox, 0, 4ull * 5000 * 4 * 4, stream);
  hipMemsetAsync(csc,  0, 4ull * 5000 * 4, stream);
  hipMemsetAsync(ccls, 0, 4ull * 5000 * 4, stream);
  hipMemsetAsync(cgid, 0, 4ull * 5000 * 4, stream);
  hipMemsetAsync(thr,  0, 20ull * 8 * 4, stream);

  wtrans_k<<<1024, 256, 0, stream>>>(cls_tw, bbox_tw, wt);

  const size_t LSTRIDE = 3ull * 589824;  // shorts per conv layer (3 planes)
  dim3 cg(nTiles, 2, 4);

  // cls tower: prep->A, A->B->A->B->A, head(A)
  prep_all_k<<<dim3(nPrep, 4), 256, 0, stream>>>(p3, p4, p5, p6, p7, bufA, G);
  conv_all_k<<<cg, 256, 0, stream>>>(bufA, wt + 0 * LSTRIDE, cls_tb + 0 * 256, bufB, G);
  conv_all_k<<<cg, 256, 0, stream>>>(bufB, wt + 1 * LSTRIDE, cls_tb + 1 * 256, bufA, G);
  conv_all_k<<<cg, 256, 0, stream>>>(bufA, wt + 2 * LSTRIDE, cls_tb + 2 * 256, bufB, G);
  conv_all_k<<<cg, 256, 0, stream>>>(bufB, wt + 3 * LSTRIDE, cls_tb + 3 * 256, bufA, G);
  cls_head_k<<<dim3(nPrep, 4), 256, 0, stream>>>(bufA, wcls, bcls, score, G);

  // bbox tower: re-prep->B, B->A->B->A->B, head(B)
  prep_all_k<<<dim3(nPrep, 4), 256, 0, stream>>>(p3, p4, p5, p6, p7, bufB, G);
  conv_all_k<<<cg, 256, 0, stream>>>(bufB, wt + 4 * LSTRIDE, bbox_tb + 0 * 256, bufA, G);
  conv_all_k<<<cg, 256, 0, stream>>>(bufA, wt + 5 * LSTRIDE, bbox_tb + 1 * 256, bufB, G);
  conv_all_k<<<cg, 256, 0, stream>>>(bufB, wt + 6 * LSTRIDE, bbox_tb + 2 * 256, bufA, G);
  conv_all_k<<<cg, 256, 0, stream>>>(bufA, wt + 7 * LSTRIDE, bbox_tb + 3 * 256, bufB, G);
  box_head_k<<<dim3(nBoxB, 4), 256, 0, stream>>>(bufB, wbox, bbox_b, wctr, bctr, scales,
                                                 score, deltas, G);

  // exact top-1000 per (level, image)
  const int hb = 196;
  for (int phase = 0; phase < 3; ++phase) {
    hipMemsetAsync(hist, 0, 20ull * 2048 * 4, stream);
    hist_k<<<dim3(hb, 20), 256, 0, stream>>>(score, thr, hist, phase, G);
    scan_k<<<20, 256, 0, stream>>>(hist, thr, phase);
  }
  select_k<<<dim3(hb, 20), 256, 0, stream>>>(score, deltas, thr, cbox, csc, ccls, cgid, G);

  nms_k<<<4, 256, 0, stream>>>(cbox, csc, ccls, cgid, out);
}

// Round 7
// 3734.055 us; speedup vs baseline: 1.1434x; 1.1434x over previous
//
#include <hip/hip_runtime.h>
#include <math.h>

typedef short s8v __attribute__((ext_vector_type(8)));
typedef short s4v __attribute__((ext_vector_type(4)));
typedef float f4v __attribute__((ext_vector_type(4)));

__device__ __forceinline__ float sigf(float x) { return 1.f / (1.f + expf(-x)); }
__device__ __forceinline__ float b2f(short v) {
  return __uint_as_float(((unsigned)(unsigned short)v) << 16);
}

#define SCALE_CLAMP 4.135166556742356f
#define IMG_SIZE 800.f
#define PLANE 14482432ull   // shorts per activation plane: sumPHW(14143)*4*256

// 3-way bf16 split (round-to-nearest): x ~= h + m + l, err ~2^-27 |x|
__device__ __forceinline__ void split3(float x, short& h, short& m, short& l) {
  unsigned u = __float_as_uint(x);
  unsigned hb = (u + 0x7FFFu + ((u >> 16) & 1u)) >> 16;
  float hf = __uint_as_float(hb << 16);
  float d1 = x - hf;
  unsigned u1 = __float_as_uint(d1);
  unsigned mb = (u1 + 0x7FFFu + ((u1 >> 16) & 1u)) >> 16;
  float mf = __uint_as_float(mb << 16);
  float d2 = d1 - mf;
  unsigned u2 = __float_as_uint(d2);
  unsigned lb = (u2 + 0x7FFFu + ((u2 >> 16) & 1u)) >> 16;
  h = (short)hb; m = (short)mb; l = (short)lb;
}

struct Geo {
  int tp[6];                 // conv tile prefix per level
  int TXa[5];
  int Ha[5], Wa[5], PWa[5], PHWa[5];
  int phwOff[5];             // PHW prefix
  int hwOff[5];              // HW prefix
  int pb[6];                 // ceil(HW/64) prefix  (prep + cls head)
  int bb[6];                 // ceil(HW/256) prefix (box head)
};

// ==================== weight split+transpose (r5 16x16 layout) ====================
// out layout (bf16 shorts): [layer8][plane3][ (tap*8+cc)*4+q ][ko 256][e 8]
__global__ __launch_bounds__(256) void wtrans_k(const float* __restrict__ cls_tw,
                                                const float* __restrict__ bbox_tw,
                                                short* __restrict__ wt)
{
  const int total = 589824;
  for (int u = blockIdx.x * 256 + threadIdx.x; u < total; u += gridDim.x * 256) {
    int layer = u / 73728;
    int r = u - layer * 73728;
    int tap = r / 8192;  r -= tap * 8192;
    int cc  = r / 1024;  r -= cc * 1024;
    int qq  = r / 256;   int ko = r - qq * 256;
    int cibase = cc * 32 + qq * 8;
    const float* src = (layer < 4) ? (cls_tw + (size_t)layer * 589824)
                                   : (bbox_tw + (size_t)(layer - 4) * 589824);
    s8v hv, mv, lv;
#pragma unroll
    for (int e = 0; e < 8; ++e) {
      float x = src[(size_t)ko * 2304 + (size_t)(cibase + e) * 9 + tap];
      short h, m, l; split3(x, h, m, l);
      hv[e] = h; mv[e] = m; lv[e] = l;
    }
    size_t dbase = (size_t)layer * 1769472 + (((size_t)tap * 8 + cc) * 4 + qq) * 2048 + (size_t)ko * 8;
    *(s8v*)(wt + dbase) = hv;
    *(s8v*)(wt + dbase + 589824) = mv;
    *(s8v*)(wt + dbase + 2 * 589824) = lv;
  }
}

// ==================== NCHW fp32 -> padded split-plane bf16x3 (all levels) ====================
__global__ __launch_bounds__(256) void prep_all_k(const float* __restrict__ p3, const float* __restrict__ p4,
                                                  const float* __restrict__ p5, const float* __restrict__ p6,
                                                  const float* __restrict__ p7,
                                                  short* __restrict__ out, Geo g)
{
  __shared__ float tl[64][260];
  int bx = blockIdx.x, t = threadIdx.x, n = blockIdx.y;
  int l = 0; while (l < 4 && bx >= g.pb[l + 1]) ++l;
  const float* in = (l == 0) ? p3 : (l == 1) ? p4 : (l == 2) ? p5 : (l == 3) ? p6 : p7;
  int H = g.Ha[l], W = g.Wa[l], PW = g.PWa[l], PHW = g.PHWa[l], HW = H * W;
  int P0 = (bx - g.pb[l]) * 64;
  const float* inN = in + (size_t)n * HW * 256;
  int sub = t >> 6, pl = t & 63;
  int pos = P0 + pl;
  for (int i = 0; i < 64; ++i) {
    int ci = i * 4 + sub;
    tl[pl][ci] = (pos < HW) ? inN[(size_t)ci * HW + pos] : 0.f;
  }
  __syncthreads();
  int pl2 = t >> 2, cq = (t & 3) * 64;
  int pos2 = P0 + pl2;
  if (pos2 < HW) {
    int y = pos2 / W, x = pos2 - y * W;
    size_t oo = ((size_t)g.phwOff[l] * 4 + (size_t)n * PHW + (size_t)(y + 1) * PW + (x + 1)) * 256 + cq;
#pragma unroll
    for (int grp = 0; grp < 8; ++grp) {
      s8v hv, mv, lv;
#pragma unroll
      for (int e = 0; e < 8; ++e) {
        short h, m, lo; split3(tl[pl2][cq + grp * 8 + e], h, m, lo);
        hv[e] = h; mv[e] = m; lv[e] = lo;
      }
      *(s8v*)(out + oo + grp * 8) = hv;
      *(s8v*)(out + PLANE + oo + grp * 8) = mv;
      *(s8v*)(out + 2 * PLANE + oo + grp * 8) = lv;
    }
  }
}

// ==================== MFMA conv 3x3 + bias + relu (16x16x32, BOTH TOWERS fused) ====================
// blockIdx.z: tower = z>>2 (0:cls 1:bbox), n = z&3. Serial fallback launches with z-dim 4.
// Internals identical to round-5 (420us/dispatch, MfmaUtil 50%): LDS act double-buffer +
// global_load_lds DMA staging, per-wave weight reg double-buffer, 1 barrier/cc.
__global__ __launch_bounds__(256, 2) void conv_all_k(const short* __restrict__ in0,
                                                     const short* __restrict__ in1,
                                                     const short* __restrict__ wt0,
                                                     const short* __restrict__ wt1,
                                                     const float* __restrict__ bias0,
                                                     const float* __restrict__ bias1,
                                                     short* __restrict__ out0,
                                                     short* __restrict__ out1, Geo g)
{
  __shared__ short act_s[2 * 3 * 768 * 8];  // [buf][plane][768 pos][8ci] = 73.7 KB

  const int t = threadIdx.x;
  const int lane = t & 63, wave = t >> 6;
  const int wcol = wave & 1, wko = wave >> 1;
  const int tower = blockIdx.z >> 2;
  const int n = blockIdx.z & 3;
  const short* in   = tower ? in1 : in0;
  const short* wtL  = tower ? wt1 : wt0;
  const float* bias = tower ? bias1 : bias0;
  short* out        = tower ? out1 : out0;
  const int ko0 = blockIdx.y * 128;
  int bx = blockIdx.x;
  int l = 0; while (l < 4 && bx >= g.tp[l + 1]) ++l;
  const int H = g.Ha[l], W = g.Wa[l], PW = g.PWa[l], PHW = g.PHWa[l];
  const int lt = bx - g.tp[l];
  const int TX = g.TXa[l];
  const int ty = lt / TX, tx = lt - ty * TX;
  const int R0 = ty * 8, C0 = tx * 16;
  const size_t bi = ((size_t)g.phwOff[l] * 4 + (size_t)n * PHW) * 256;
  const short* inN = in + bi;
  short* outN = out + bi;

  const int r = lane & 15, q = lane >> 4;
  const int cb = wcol * 8;
  const short* wlane = wtL + (size_t)q * 2048 + (size_t)(ko0 + wko * 64 + r) * 8;

  // per-thread source offsets for the 3 staging sub-iterations (j = t + k*256)
  int soff[3];
#pragma unroll
  for (int k = 0; k < 3; ++k) {
    int j = t + k * 256; if (j > 719) j = 719;
    int qq = j / 180, pos = j - qq * 180;
    int row = pos / 18, col = pos - row * 18;
    int prow = R0 + row; if (prow > H + 1) prow = H + 1;
    int pcol = C0 + col; if (pcol > W + 1) pcol = W + 1;
    soff[k] = (prow * PW + pcol) * 256 + qq * 8;
  }

  f4v acc[4][4];
#pragma unroll
  for (int mi = 0; mi < 4; ++mi)
#pragma unroll
    for (int ni = 0; ni < 4; ++ni) { f4v z = {0.f, 0.f, 0.f, 0.f}; acc[mi][ni] = z; }

  auto stage = [&](int cc, int buf) {
#pragma unroll
    for (int k = 0; k < 3; ++k)
#pragma unroll
      for (int p = 0; p < 3; ++p) {
        const short* src = inN + (size_t)p * PLANE + (size_t)(soff[k] + cc * 32);
        short* dst = &act_s[(size_t)buf * 18432 + (size_t)p * 6144 + (size_t)(t + k * 256) * 8];
#if __has_builtin(__builtin_amdgcn_global_load_lds)
        __builtin_amdgcn_global_load_lds((const __attribute__((address_space(1))) void*)src,
                                         (__attribute__((address_space(3))) void*)dst, 16, 0, 0);
#else
        *(s8v*)dst = *(const s8v*)src;
#endif
      }
  };

  auto loadB = [&](s8v (&bf)[3][4], int cc2, int tap2) {
    const short* base = wlane + (size_t)(tap2 * 8 + cc2) * 8192;
#pragma unroll
    for (int p = 0; p < 3; ++p)
#pragma unroll
      for (int ni = 0; ni < 4; ++ni)
        bf[p][ni] = *(const s8v*)(base + (size_t)p * 589824 + ni * 128);
  };

  auto runTap = [&](const s8v (&bf)[3][4], int dy, int dx, int buf) {
    s8v afr[3][4];
    const int sbase = buf * 18432;
#pragma unroll
    for (int mi = 0; mi < 4; ++mi) {
      int sl = q * 180 + (2 * mi + (r >> 3) + dy) * 18 + (cb + (r & 7) + dx);
      afr[0][mi] = *(const s8v*)&act_s[sbase + sl * 8];
      afr[1][mi] = *(const s8v*)&act_s[sbase + 6144 + sl * 8];
      afr[2][mi] = *(const s8v*)&act_s[sbase + 12288 + sl * 8];
    }
    const int PA[6] = {0, 0, 1, 1, 0, 2};
    const int PB[6] = {0, 1, 0, 1, 2, 0};
#pragma unroll
    for (int pp = 0; pp < 6; ++pp) {
#pragma unroll
      for (int mi = 0; mi < 4; ++mi)
#pragma unroll
        for (int ni = 0; ni < 4; ++ni)
          acc[mi][ni] = __builtin_amdgcn_mfma_f32_16x16x32_bf16(
              afr[PA[pp]][mi], bf[PB[pp]][ni], acc[mi][ni], 0, 0, 0);
    }
  };

  s8v bfrA[3][4], bfrB[3][4];
  stage(0, 0);
  loadB(bfrA, 0, 0);
  __syncthreads();            // compiler drains vmcnt(0) before s_barrier

  int cur = 0;
  for (int cc = 0; cc < 8; ++cc) {
    if (cc < 7) stage(cc + 1, cur ^ 1);   // DMA hides under the 864 MFMAs below
#pragma unroll
    for (int tap = 0; tap < 9; ++tap) {
      const int dy = tap / 3, dx = tap - dy * 3;
      if (tap < 8) {
        if (tap & 1) loadB(bfrA, cc, tap + 1); else loadB(bfrB, cc, tap + 1);
      } else if (cc < 7) {
        loadB(bfrB, cc + 1, 0);
      }
      if (tap & 1) runTap(bfrB, dy, dx, cur); else runTap(bfrA, dy, dx, cur);
    }
    if (cc < 7) {
#pragma unroll
      for (int p = 0; p < 3; ++p)
#pragma unroll
        for (int ni = 0; ni < 4; ++ni) bfrA[p][ni] = bfrB[p][ni];
    }
    __syncthreads();          // vmcnt drain (DMA landed) + all waves done with act_s[cur]
    cur ^= 1;
  }

  // epilogue: bias + relu + split3, store 3 bf16 planes (masked)
#pragma unroll
  for (int mi = 0; mi < 4; ++mi) {
#pragma unroll
    for (int ni = 0; ni < 4; ++ni) {
      int ko = ko0 + wko * 64 + ni * 16 + r;
      float bv = bias[ko];
#pragma unroll
      for (int reg = 0; reg < 4; ++reg) {
        int rm = q * 4 + reg;
        int orow = R0 + 2 * mi + (rm >> 3);
        int ocol = C0 + cb + (rm & 7);
        if (orow < H && ocol < W) {
          float vv = fmaxf(acc[mi][ni][reg] + bv, 0.f);
          short h, m, lo; split3(vv, h, m, lo);
          size_t oo = ((size_t)(orow + 1) * PW + (ocol + 1)) * 256 + ko;
          outN[oo] = h; outN[PLANE + oo] = m; outN[2 * PLANE + oo] = lo;
        }
      }
    }
  }
}

// ==================== cls head (all levels): 1x1x80 + sigmoid ====================
__global__ __launch_bounds__(256) void cls_head_k(const short* __restrict__ act,
                                                  const float* __restrict__ wcls,
                                                  const float* __restrict__ bcls,
                                                  float* __restrict__ score, Geo g)
{
  __shared__ int   p2s[64];
  __shared__ float as_[64][69];
  __shared__ float ws_[64][84];
  const int t = threadIdx.x;
  const int n = blockIdx.y;
  int bx = blockIdx.x;
  int l = 0; while (l < 4 && bx >= g.pb[l + 1]) ++l;
  const int H = g.Ha[l], W = g.Wa[l], PW = g.PWa[l], PHW = g.PHWa[l], HW = H * W;
  const int P0 = (bx - g.pb[l]) * 64;
  if (t < 64) {
    int p = P0 + t; if (p >= HW) p = HW - 1;
    int y = p / W, x = p - y * W;
    p2s[t] = (y + 1) * PW + x + 1;
  }
  __syncthreads();
  float accv[4][5];
#pragma unroll
  for (int i = 0; i < 4; ++i)
#pragma unroll
    for (int j = 0; j < 5; ++j) accv[i][j] = 0.f;

  const short* actN = act + ((size_t)g.phwOff[l] * 4 + (size_t)n * PHW) * 256;
  const int pg = t >> 4, cg = t & 15;

  for (int c0 = 0; c0 < 256; c0 += 64) {
    for (int i = t; i < 1024; i += 256) {
      int pos = i >> 4, c4 = i & 15;
      size_t o = (size_t)p2s[pos] * 256 + c0 + c4 * 4;
      s4v hv = *(const s4v*)(actN + o);
      s4v mv = *(const s4v*)(actN + PLANE + o);
      s4v lv = *(const s4v*)(actN + 2 * PLANE + o);
      float* dst = &as_[pos][c4 * 4];
#pragma unroll
      for (int e = 0; e < 4; ++e) dst[e] = b2f(hv[e]) + b2f(mv[e]) + b2f(lv[e]);
    }
    for (int i = t; i < 1280; i += 256) {
      int c = i >> 4, c4 = i & 15;
      float4 v = *(const float4*)(wcls + (size_t)c * 256 + c0 + c4 * 4);
      ws_[c4 * 4 + 0][c] = v.x; ws_[c4 * 4 + 1][c] = v.y;
      ws_[c4 * 4 + 2][c] = v.z; ws_[c4 * 4 + 3][c] = v.w;
    }
    __syncthreads();
#pragma unroll 8
    for (int ci = 0; ci < 64; ++ci) {
#pragma unroll
      for (int i = 0; i < 4; ++i) {
        float a = as_[pg * 4 + i][ci];
#pragma unroll
        for (int j = 0; j < 5; ++j)
          accv[i][j] = fmaf(a, ws_[ci][cg * 5 + j], accv[i][j]);
      }
    }
    __syncthreads();
  }
  float* sB = score + ((size_t)g.hwOff[l] * 4 + (size_t)n * HW) * 80;
#pragma unroll
  for (int i = 0; i < 4; ++i) {
    int p = P0 + pg * 4 + i;
    if (p >= HW) continue;
#pragma unroll
    for (int j = 0; j < 5; ++j) {
      int c = cg * 5 + j;
      sB[(size_t)p * 80 + c] = sigf(accv[i][j] + bcls[c]);
    }
  }
}

// ==================== box head (all levels) ====================
__global__ __launch_bounds__(256) void box_head_k(const short* __restrict__ act,
                                                  const float* __restrict__ wbox,
                                                  const float* __restrict__ bb,
                                                  const float* __restrict__ wctr,
                                                  const float* __restrict__ bc,
                                                  const float* __restrict__ scales,
                                                  float* __restrict__ score,
                                                  float* __restrict__ deltas, Geo g)
{
  int n = blockIdx.y;
  int bx = blockIdx.x;
  int l = 0; while (l < 4 && bx >= g.bb[l + 1]) ++l;
  const int H = g.Ha[l], W = g.Wa[l], PW = g.PWa[l], PHW = g.PHWa[l], HW = H * W;
  int p = (bx - g.bb[l]) * 256 + threadIdx.x;
  if (p >= HW) return;
  int y = p / W, x = p - y * W;
  const short* a = act + ((size_t)g.phwOff[l] * 4 + (size_t)n * PHW + (size_t)(y + 1) * PW + x + 1) * 256;
  float d0 = 0, d1 = 0, d2 = 0, d3 = 0, ct = 0;
  for (int gI = 0; gI < 32; ++gI) {
    s8v hv = *(const s8v*)(a + gI * 8);
    s8v mv = *(const s8v*)(a + PLANE + gI * 8);
    s8v lv = *(const s8v*)(a + 2 * PLANE + gI * 8);
#pragma unroll
    for (int e = 0; e < 8; ++e) {
      float av = b2f(hv[e]) + b2f(mv[e]) + b2f(lv[e]);
      int c = gI * 8 + e;
      d0 = fmaf(av, wbox[c], d0);
      d1 = fmaf(av, wbox[256 + c], d1);
      d2 = fmaf(av, wbox[512 + c], d2);
      d3 = fmaf(av, wbox[768 + c], d3);
      ct = fmaf(av, wctr[c], ct);
    }
  }
  float sl = scales[l];
  float* dd = deltas + ((size_t)g.hwOff[l] * 4 + (size_t)n * HW + p) * 4;
  dd[0] = sl * (d0 + bb[0]); dd[1] = sl * (d1 + bb[1]);
  dd[2] = sl * (d2 + bb[2]); dd[3] = sl * (d3 + bb[3]);
  float sct = sigf(ct + bc[0]);
  float* sp = score + ((size_t)g.hwOff[l] * 4 + (size_t)n * HW + p) * 80;
#pragma unroll
  for (int i = 0; i < 20; ++i) {
    float4 v = ((float4*)sp)[i];
    v.x *= sct; v.y *= sct; v.z *= sct; v.w *= sct;
    v.x = (v.x > 0.05f) ? v.x : 0.f;
    v.y = (v.y > 0.05f) ? v.y : 0.f;
    v.z = (v.z > 0.05f) ? v.z : 0.f;
    v.w = (v.w > 0.05f) ? v.w : 0.f;
    ((float4*)sp)[i] = v;
  }
}

// ==================== exact top-1000: 3-pass bit histogram, 20 (level,image) groups ====================
__global__ __launch_bounds__(256) void hist_k(const float* __restrict__ score,
                                              const unsigned* __restrict__ thr,
                                              unsigned* __restrict__ hist, int phase, Geo g)
{
  const int grp = blockIdx.y;
  const int l = grp >> 2, n = grp & 3;
  const int HW = g.Ha[l] * g.Wa[l];
  const int M = HW * 80;
  const float* s = score + ((size_t)g.hwOff[l] * 4 + (size_t)n * HW) * 80;
  unsigned* h = hist + grp * 2048;
  const unsigned* tr = thr + grp * 8;
  __shared__ unsigned lh[2048];
  for (int i = threadIdx.x; i < 2048; i += 256) lh[i] = 0u;
  __syncthreads();
  unsigned B1 = 0, pref = 0;
  if (phase == 1) B1 = tr[0];
  if (phase == 2) pref = (tr[0] << 11) | tr[1];
  for (int idx = blockIdx.x * 256 + threadIdx.x; idx < M; idx += gridDim.x * 256) {
    float v = s[idx];
    if (v > 0.f) {
      unsigned b = __float_as_uint(v);
      if (phase == 0) atomicAdd(&lh[b >> 20], 1u);
      else if (phase == 1) { if ((b >> 20) == B1) atomicAdd(&lh[(b >> 9) & 0x7FFu], 1u); }
      else { if ((b >> 9) == pref) atomicAdd(&lh[b & 0x1FFu], 1u); }
    }
  }
  __syncthreads();
  for (int i = threadIdx.x; i < 2048; i += 256) { unsigned v = lh[i]; if (v) atomicAdd(&h[i], v); }
}

__global__ __launch_bounds__(256) void scan_k(unsigned* __restrict__ hist,
                                              unsigned* __restrict__ thr, int phase)
{
  const int grp = blockIdx.x, t = threadIdx.x;
  unsigned* h  = hist + grp * 2048;
  unsigned* tr = thr + grp * 8;
  const int nb = (phase == 2) ? 512 : 2048;
  const int PB = nb / 256;
  unsigned target = 1000u;
  bool dead = false;
  if (phase >= 1) {
    target = 1000u - tr[2];
    if (tr[0] == 0xFFFFFFFFu) dead = true;
    if (phase == 2 && tr[1] == 0xFFFFFFFFu) dead = true;
  }
  __shared__ unsigned ps[256];
  __shared__ unsigned s_tot;
  const int hi = nb - t * PB;
  unsigned lsum = 0;
  for (int k = 0; k < PB; ++k) lsum += h[hi - 1 - k];
  ps[t] = lsum;
  __syncthreads();
  if (t == 0) {
    unsigned cum = 0;
    for (int i = 0; i < 256; ++i) { unsigned tmp = ps[i]; ps[i] = cum; cum += tmp; }
    s_tot = cum;
  }
  __syncthreads();
  unsigned exc = ps[t], tot = s_tot;
  if (!dead && tot >= target) {
    if (exc < target && exc + lsum >= target) {
      unsigned cum = exc; int bf = 0; unsigned above = 0;
      for (int k = 0; k < PB; ++k) {
        int bidx = hi - 1 - k;
        unsigned c = h[bidx];
        if (cum < target && cum + c >= target) { bf = bidx; above = cum; }
        cum += c;
      }
      if (phase == 0)      { tr[0] = (unsigned)bf; tr[2] = above; }
      else if (phase == 1) { tr[1] = (unsigned)bf; tr[2] = tr[2] + above; }
      else {
        unsigned T = (tr[0] << 20) | (tr[1] << 9) | (unsigned)bf;
        tr[3] = T; tr[4] = target - above;
      }
    }
  } else if (t == 0) {
    if (phase == 0)      { tr[0] = 0xFFFFFFFFu; tr[2] = 0u; }
    else if (phase == 1) { tr[1] = 0xFFFFFFFFu; }
    else                 { tr[3] = 0u; tr[4] = 0u; }
  }
  if (phase == 2 && t == 0) { tr[5] = 0u; tr[6] = 0u; }
}

// ==================== select + decode ====================
__global__ __launch_bounds__(256) void select_k(const float* __restrict__ score,
                                                const float* __restrict__ deltas,
                                                unsigned* __restrict__ thr,
                                                float* __restrict__ cbox, float* __restrict__ csc,
                                                float* __restrict__ ccls, float* __restrict__ cgid,
                                                Geo g)
{
  const int grp = blockIdx.y;
  const int l = grp >> 2, n = grp & 3;
  const int W = g.Wa[l];
  const int HW = g.Ha[l] * W;
  const int M = HW * 80;
  const float stride_ = (float)(8 << l);
  const float* s = score + ((size_t)g.hwOff[l] * 4 + (size_t)n * HW) * 80;
  const float* dBase = deltas + ((size_t)g.hwOff[l] * 4 + (size_t)n * HW) * 4;
  unsigned* tr = thr + grp * 8;
  const unsigned T = tr[3], need = tr[4];
  for (int idx = blockIdx.x * 256 + threadIdx.x; idx < M; idx += gridDim.x * 256) {
    float v = s[idx];
    if (!(v > 0.f)) continue;
    unsigned b = __float_as_uint(v);
    int slot = -1;
    if (b > T) slot = (int)atomicAdd(&tr[5], 1u);
    else if (b == T) {
      unsigned e = atomicAdd(&tr[6], 1u);
      if (e < need) slot = (int)(1000u - need + e);
    }
    if (slot < 0) continue;
    int p = idx / 80, c = idx - p * 80;
    int y = p / W, x = p - y * W;
    const float* d = dBase + (size_t)p * 4;
    float sz  = 8.f * stride_;
    float acx = ((float)x + 0.5f) * stride_;
    float acy = ((float)y + 0.5f) * stride_;
    float dx = d[0] / 10.f, dy = d[1] / 10.f;
    float dw = fminf(d[2] / 5.f, SCALE_CLAMP);
    float dh = fminf(d[3] / 5.f, SCALE_CLAMP);
    float pcx = dx * sz + acx;
    float pcy = dy * sz + acy;
    float pw = expf(dw) * sz;
    float ph = expf(dh) * sz;
    float x1 = pcx - 0.5f * pw, y1_ = pcy - 0.5f * ph;
    float x2 = pcx + 0.5f * pw, y2_ = pcy + 0.5f * ph;
    x1  = fminf(fmaxf(x1, 0.f),  IMG_SIZE);
    y1_ = fminf(fmaxf(y1_, 0.f), IMG_SIZE);
    x2  = fminf(fmaxf(x2, 0.f),  IMG_SIZE);
    y2_ = fminf(fmaxf(y2_, 0.f), IMG_SIZE);
    int cslot = n * 5000 + l * 1000 + slot;
    ((float4*)cbox)[cslot] = make_float4(x1, y1_, x2, y2_);
    csc[cslot]  = sqrtf(v);
    ccls[cslot] = (float)c;
    cgid[cslot] = (float)(((unsigned)l << 20) | (unsigned)idx);
  }
}

// ==================== class-aware greedy NMS ====================
__global__ __launch_bounds__(256) void nms_k(const float* __restrict__ cbox,
                                             const float* __restrict__ csc,
                                             const float* __restrict__ ccls,
                                             const float* __restrict__ cgid,
                                             float* __restrict__ outp)
{
  const int n = blockIdx.x, t = threadIdx.x;
  float sc[20], cl[20], gid[20], bx[20][4];
#pragma unroll
  for (int j = 0; j < 20; ++j) {
    int gidx = j * 256 + t;
    if (gidx < 5000) {
      sc[j] = csc[n * 5000 + gidx];
      float4 b = ((const float4*)cbox)[n * 5000 + gidx];
      bx[j][0] = b.x; bx[j][1] = b.y; bx[j][2] = b.z; bx[j][3] = b.w;
      cl[j]  = ccls[n * 5000 + gidx];
      gid[j] = cgid[n * 5000 + gidx];
    } else { sc[j] = -2.f; bx[j][0] = bx[j][1] = bx[j][2] = bx[j][3] = 0.f; cl[j] = 0.f; gid[j] = 1e9f; }
  }
  __shared__ float rv[4]; __shared__ int rg[4]; __shared__ float rgid[4];
  __shared__ float sbox[4]; __shared__ float scls; __shared__ float sval; __shared__ int sgi;

  for (int it = 0; it < 100; ++it) {
    float bv = -3.f; int bg = 0; float bgid = 2e9f;
#pragma unroll
    for (int j = 0; j < 20; ++j) {
      bool better = (sc[j] > bv) || (sc[j] == bv && gid[j] < bgid);
      if (better) { bv = sc[j]; bg = j * 256 + t; bgid = gid[j]; }
    }
    for (int off = 32; off; off >>= 1) {
      float ov = __shfl_xor(bv, off);
      int   og = __shfl_xor(bg, off);
      float oi = __shfl_xor(bgid, off);
      bool better = (ov > bv) || (ov == bv && oi < bgid);
      if (better) { bv = ov; bg = og; bgid = oi; }
    }
    int wid = t >> 6;
    if ((t & 63) == 0) { rv[wid] = bv; rg[wid] = bg; rgid[wid] = bgid; }
    __syncthreads();
    if (t == 0) {
      float fv = rv[0]; int fg = rg[0]; float fi = rgid[0];
      for (int w = 1; w < 4; ++w) {
        bool better = (rv[w] > fv) || (rv[w] == fv && rgid[w] < fi);
        if (better) { fv = rv[w]; fg = rg[w]; fi = rgid[w]; }
      }
      sval = fv; sgi = fg;
    }
    __syncthreads();
    float best_v = sval; int best_g = sgi;
    if (t == (best_g & 255)) {
      int j = best_g >> 8;
      sbox[0] = bx[j][0]; sbox[1] = bx[j][1]; sbox[2] = bx[j][2]; sbox[3] = bx[j][3];
      scls = cl[j];
    }
    __syncthreads();
    bool valid = best_v > 0.f;
    if (t == 0) {
      int base = n * 100 + it;
      outp[base * 4 + 0] = valid ? sbox[0] : 0.f;
      outp[base * 4 + 1] = valid ? sbox[1] : 0.f;
      outp[base * 4 + 2] = valid ? sbox[2] : 0.f;
      outp[base * 4 + 3] = valid ? sbox[3] : 0.f;
      outp[1600 + base] = valid ? best_v : 0.f;
      outp[2000 + base] = valid ? scls : -1.f;
    }
    float off_ = scls * (2.f * IMG_SIZE);
    float e0 = sbox[0] + off_, e1 = sbox[1] + off_, e2 = sbox[2] + off_, e3 = sbox[3] + off_;
    float a1 = (e2 - e0) * (e3 - e1);
#pragma unroll
    for (int j = 0; j < 20; ++j) {
      float o_ = cl[j] * (2.f * IMG_SIZE);
      float f0 = bx[j][0] + o_, f1 = bx[j][1] + o_, f2 = bx[j][2] + o_, f3 = bx[j][3] + o_;
      float xx1 = fmaxf(e0, f0), yy1 = fmaxf(e1, f1);
      float xx2 = fminf(e2, f2), yy2 = fminf(e3, f3);
      float inter = fmaxf(xx2 - xx1, 0.f) * fmaxf(yy2 - yy1, 0.f);
      float a2 = (f2 - f0) * (f3 - f1);
      float iou = inter / (a1 + a2 - inter + 1e-9f);
      if (iou > 0.6f) sc[j] = -1.f;
      if ((j * 256 + t) == best_g) sc[j] = -1.f;
    }
    __syncthreads();
  }
}

// ==================== host ====================
extern "C" void kernel_launch(void* const* d_in, const int* in_sizes, int n_in,
                              void* d_out, int out_size, void* d_ws, size_t ws_size,
                              hipStream_t stream)
{
  (void)in_sizes; (void)n_in; (void)out_size;
  const float* p3 = (const float*)d_in[0];
  const float* p4 = (const float*)d_in[1];
  const float* p5 = (const float*)d_in[2];
  const float* p6 = (const float*)d_in[3];
  const float* p7 = (const float*)d_in[4];
  const float* cls_tw  = (const float*)d_in[5];
  const float* cls_tb  = (const float*)d_in[6];
  const float* bbox_tw = (const float*)d_in[7];
  const float* bbox_tb = (const float*)d_in[8];
  const float* wcls    = (const float*)d_in[9];
  const float* bcls    = (const float*)d_in[10];
  const float* wbox    = (const float*)d_in[11];
  const float* bbox_b  = (const float*)d_in[12];
  const float* wctr    = (const float*)d_in[13];
  const float* bctr    = (const float*)d_in[14];
  const float* scales  = (const float*)d_in[15];
  float* out = (float*)d_out;

  // geometry
  Geo G;
  const int Hs[5] = {100, 50, 25, 13, 7};
  {
    int tpre = 0, ppre = 0, bpre = 0, phw = 0, hw = 0;
    for (int l = 0; l < 5; ++l) {
      int H = Hs[l], W = Hs[l];
      G.Ha[l] = H; G.Wa[l] = W; G.PWa[l] = W + 2; G.PHWa[l] = (H + 2) * (W + 2);
      G.TXa[l] = (W + 15) / 16;
      int TY = (H + 7) / 8;
      G.tp[l] = tpre;  tpre += G.TXa[l] * TY;
      G.pb[l] = ppre;  ppre += (H * W + 63) / 64;
      G.bb[l] = bpre;  bpre += (H * W + 255) / 256;
      G.phwOff[l] = phw; phw += G.PHWa[l];
      G.hwOff[l]  = hw;  hw  += H * W;
    }
    G.tp[5] = tpre; G.pb[5] = ppre; G.bb[5] = bpre;
  }
  const int nTiles = G.tp[5];   // 130
  const int nPrep  = G.pb[5];   // 211
  const int nBoxB  = G.bb[5];   // 55
  const int sumHW = 13343;

  char* ws = (char*)d_ws;
  size_t off = 0;
  auto alloc = [&](size_t bytes) -> void* {
    off = (off + 255) & ~(size_t)255;
    void* p = ws + off; off += bytes; return p;
  };
  const size_t bufBytes = 3ull * PLANE * 2;   // one split-plane act buffer = 86.9 MB
  // fixed allocations (both paths)
  short* wt     = (short*)alloc((size_t)8 * 3 * 589824 * 2);
  float* score  = (float*)alloc((size_t)sumHW * 4 * 80 * 4);
  float* deltas = (float*)alloc((size_t)sumHW * 4 * 4 * 4);
  float* cbox   = (float*)alloc(4ull * 5000 * 4 * 4);
  float* csc    = (float*)alloc(4ull * 5000 * 4);
  float* ccls   = (float*)alloc(4ull * 5000 * 4);
  float* cgid   = (float*)alloc(4ull * 5000 * 4);
  unsigned* hist = (unsigned*)alloc(20ull * 2048 * 4);
  unsigned* thr  = (unsigned*)alloc(20ull * 8 * 4);
  const size_t fixedEnd = off;
  const bool fused = (ws_size >= fixedEnd + 4 * (bufBytes + 256) + 1024);

  hipMemsetAsync(cbox, 0, 4ull * 5000 * 4 * 4, stream);
  hipMemsetAsync(csc,  0, 4ull * 5000 * 4, stream);
  hipMemsetAsync(ccls, 0, 4ull * 5000 * 4, stream);
  hipMemsetAsync(cgid, 0, 4ull * 5000 * 4, stream);
  hipMemsetAsync(thr,  0, 20ull * 8 * 4, stream);

  wtrans_k<<<1024, 256, 0, stream>>>(cls_tw, bbox_tw, wt);

  const size_t LSTRIDE = 3ull * 589824;  // shorts per conv layer (3 planes)
  short* clsFinal;
  short* boxFinal;

  if (fused) {
    short* P = (short*)alloc(bufBytes);
    short* A = (short*)alloc(bufBytes);
    short* B = (short*)alloc(bufBytes);
    short* C = (short*)alloc(bufBytes);
    hipMemsetAsync(P, 0, bufBytes, stream);
    hipMemsetAsync(A, 0, bufBytes, stream);
    hipMemsetAsync(B, 0, bufBytes, stream);
    hipMemsetAsync(C, 0, bufBytes, stream);

    prep_all_k<<<dim3(nPrep, 4), 256, 0, stream>>>(p3, p4, p5, p6, p7, P, G);

    dim3 cg(nTiles, 2, 8);  // z: tower*4 + image
    // L0: (P,P) -> (A,B)
    conv_all_k<<<cg, 256, 0, stream>>>(P, P, wt + 0 * LSTRIDE, wt + 4 * LSTRIDE,
                                       cls_tb + 0 * 256, bbox_tb + 0 * 256, A, B, G);
    // L1: (A,B) -> (C,P)
    conv_all_k<<<cg, 256, 0, stream>>>(A, B, wt + 1 * LSTRIDE, wt + 5 * LSTRIDE,
                                       cls_tb + 1 * 256, bbox_tb + 1 * 256, C, P, G);
    // L2: (C,P) -> (A,B)
    conv_all_k<<<cg, 256, 0, stream>>>(C, P, wt + 2 * LSTRIDE, wt + 6 * LSTRIDE,
                                       cls_tb + 2 * 256, bbox_tb + 2 * 256, A, B, G);
    // L3: (A,B) -> (C,P)
    conv_all_k<<<cg, 256, 0, stream>>>(A, B, wt + 3 * LSTRIDE, wt + 7 * LSTRIDE,
                                       cls_tb + 3 * 256, bbox_tb + 3 * 256, C, P, G);
    clsFinal = C; boxFinal = P;
  } else {
    short* A = (short*)alloc(bufBytes);
    short* B = (short*)alloc(bufBytes);
    hipMemsetAsync(A, 0, bufBytes, stream);
    hipMemsetAsync(B, 0, bufBytes, stream);
    dim3 cg(nTiles, 2, 4);  // z: image only (tower 0 slots)
    // cls tower: prep->A, A->B->A->B->A
    prep_all_k<<<dim3(nPrep, 4), 256, 0, stream>>>(p3, p4, p5, p6, p7, A, G);
    conv_all_k<<<cg, 256, 0, stream>>>(A, A, wt + 0 * LSTRIDE, wt + 0 * LSTRIDE,
                                       cls_tb + 0 * 256, cls_tb + 0 * 256, B, B, G);
    conv_all_k<<<cg, 256, 0, stream>>>(B, B, wt + 1 * LSTRIDE, wt + 1 * LSTRIDE,
                                       cls_tb + 1 * 256, cls_tb + 1 * 256, A, A, G);
    conv_all_k<<<cg, 256, 0, stream>>>(A, A, wt + 2 * LSTRIDE, wt + 2 * LSTRIDE,
                                       cls_tb + 2 * 256, cls_tb + 2 * 256, B, B, G);
    conv_all_k<<<cg, 256, 0, stream>>>(B, B, wt + 3 * LSTRIDE, wt + 3 * LSTRIDE,
                                       cls_tb + 3 * 256, cls_tb + 3 * 256, A, A, G);
    cls_head_k<<<dim3(nPrep, 4), 256, 0, stream>>>(A, wcls, bcls, score, G);
    // bbox tower: re-prep->B, B->A->B->A->B
    prep_all_k<<<dim3(nPrep, 4), 256, 0, stream>>>(p3, p4, p5, p6, p7, B, G);
    conv_all_k<<<cg, 256, 0, stream>>>(B, B, wt + 4 * LSTRIDE, wt + 4 * LSTRIDE,
                                       bbox_tb + 0 * 256, bbox_tb + 0 * 256, A, A, G);
    conv_all_k<<<cg, 256, 0, stream>>>(A, A, wt + 5 * LSTRIDE, wt + 5 * LSTRIDE,
                                       bbox_tb + 1 * 256, bbox_tb + 1 * 256, B, B, G);
    conv_all_k<<<cg, 256, 0, stream>>>(B, B, wt + 6 * LSTRIDE, wt + 6 * LSTRIDE,
                                       bbox_tb + 2 * 256, bbox_tb + 2 * 256, A, A, G);
    conv_all_k<<<cg, 256, 0, stream>>>(A, A, wt + 7 * LSTRIDE, wt + 7 * LSTRIDE,
                                       bbox_tb + 3 * 256, bbox_tb + 3 * 256, B, B, G);
    clsFinal = nullptr;  // cls head already ran
    boxFinal = B;
  }

  if (fused) cls_head_k<<<dim3(nPrep, 4), 256, 0, stream>>>(clsFinal, wcls, bcls, score, G);
  box_head_k<<<dim3(nBoxB, 4), 256, 0, stream>>>(boxFinal, wbox, bbox_b, wctr, bctr, scales,
                                                 score, deltas, G);

  // exact top-1000 per (level, image)
  const int hb = 196;
  for (int phase = 0; phase < 3; ++phase) {
    hipMemsetAsync(hist, 0, 20ull * 2048 * 4, stream);
    hist_k<<<dim3(hb, 20), 256, 0, stream>>>(score, thr, hist, phase, G);
    scan_k<<<20, 256, 0, stream>>>(hist, thr, phase);
  }
  select_k<<<dim3(hb, 20), 256, 0, stream>>>(score, deltas, thr, cbox, csc, ccls, cgid, G);

  nms_k<<<4, 256, 0, stream>>>(cbox, csc, ccls, cgid, out);
}

// Round 8
// 3483.150 us; speedup vs baseline: 1.2258x; 1.0720x over previous
//
#include <hip/hip_runtime.h>
#include <math.h>

typedef short s8v __attribute__((ext_vector_type(8)));
typedef short s4v __attribute__((ext_vector_type(4)));
typedef float f4v __attribute__((ext_vector_type(4)));

__device__ __forceinline__ float sigf(float x) { return 1.f / (1.f + expf(-x)); }
__device__ __forceinline__ float b2f(short v) {
  return __uint_as_float(((unsigned)(unsigned short)v) << 16);
}

#define SCALE_CLAMP 4.135166556742356f
#define IMG_SIZE 800.f
#define PLANE 14482432ull   // shorts per activation plane: sumPHW(14143)*4*256

// 3-way bf16 split (round-to-nearest): x ~= h + m + l, err ~2^-27 |x|
__device__ __forceinline__ void split3(float x, short& h, short& m, short& l) {
  unsigned u = __float_as_uint(x);
  unsigned hb = (u + 0x7FFFu + ((u >> 16) & 1u)) >> 16;
  float hf = __uint_as_float(hb << 16);
  float d1 = x - hf;
  unsigned u1 = __float_as_uint(d1);
  unsigned mb = (u1 + 0x7FFFu + ((u1 >> 16) & 1u)) >> 16;
  float mf = __uint_as_float(mb << 16);
  float d2 = d1 - mf;
  unsigned u2 = __float_as_uint(d2);
  unsigned lb = (u2 + 0x7FFFu + ((u2 >> 16) & 1u)) >> 16;
  h = (short)hb; m = (short)mb; l = (short)lb;
}

struct Geo {
  int tp[6];                 // conv tile prefix per level
  int TXa[5];
  int Ha[5], Wa[5], PWa[5], PHWa[5];
  int phwOff[5];             // PHW prefix
  int hwOff[5];              // HW prefix
  int pb[6];                 // ceil(HW/64) prefix  (prep + cls head)
  int bb[6];                 // ceil(HW/256) prefix (box head)
};

// ==================== weight split+transpose (16x16 layout) ====================
// out layout (bf16 shorts): [layer8][plane3][ (tap*8+cc)*4+q ][ko 256][e 8]
__global__ __launch_bounds__(256) void wtrans_k(const float* __restrict__ cls_tw,
                                                const float* __restrict__ bbox_tw,
                                                short* __restrict__ wt)
{
  const int total = 589824;
  for (int u = blockIdx.x * 256 + threadIdx.x; u < total; u += gridDim.x * 256) {
    int layer = u / 73728;
    int r = u - layer * 73728;
    int tap = r / 8192;  r -= tap * 8192;
    int cc  = r / 1024;  r -= cc * 1024;
    int qq  = r / 256;   int ko = r - qq * 256;
    int cibase = cc * 32 + qq * 8;
    const float* src = (layer < 4) ? (cls_tw + (size_t)layer * 589824)
                                   : (bbox_tw + (size_t)(layer - 4) * 589824);
    s8v hv, mv, lv;
#pragma unroll
    for (int e = 0; e < 8; ++e) {
      float x = src[(size_t)ko * 2304 + (size_t)(cibase + e) * 9 + tap];
      short h, m, l; split3(x, h, m, l);
      hv[e] = h; mv[e] = m; lv[e] = l;
    }
    size_t dbase = (size_t)layer * 1769472 + (((size_t)tap * 8 + cc) * 4 + qq) * 2048 + (size_t)ko * 8;
    *(s8v*)(wt + dbase) = hv;
    *(s8v*)(wt + dbase + 589824) = mv;
    *(s8v*)(wt + dbase + 2 * 589824) = lv;
  }
}

// ==================== NCHW fp32 -> padded split-plane bf16x3 (all levels) ====================
__global__ __launch_bounds__(256) void prep_all_k(const float* __restrict__ p3, const float* __restrict__ p4,
                                                  const float* __restrict__ p5, const float* __restrict__ p6,
                                                  const float* __restrict__ p7,
                                                  short* __restrict__ out, Geo g)
{
  __shared__ float tl[64][260];
  int bx = blockIdx.x, t = threadIdx.x, n = blockIdx.y;
  int l = 0; while (l < 4 && bx >= g.pb[l + 1]) ++l;
  const float* in = (l == 0) ? p3 : (l == 1) ? p4 : (l == 2) ? p5 : (l == 3) ? p6 : p7;
  int H = g.Ha[l], W = g.Wa[l], PW = g.PWa[l], PHW = g.PHWa[l], HW = H * W;
  int P0 = (bx - g.pb[l]) * 64;
  const float* inN = in + (size_t)n * HW * 256;
  int sub = t >> 6, pl = t & 63;
  int pos = P0 + pl;
  for (int i = 0; i < 64; ++i) {
    int ci = i * 4 + sub;
    tl[pl][ci] = (pos < HW) ? inN[(size_t)ci * HW + pos] : 0.f;
  }
  __syncthreads();
  int pl2 = t >> 2, cq = (t & 3) * 64;
  int pos2 = P0 + pl2;
  if (pos2 < HW) {
    int y = pos2 / W, x = pos2 - y * W;
    size_t oo = ((size_t)g.phwOff[l] * 4 + (size_t)n * PHW + (size_t)(y + 1) * PW + (x + 1)) * 256 + cq;
#pragma unroll
    for (int grp = 0; grp < 8; ++grp) {
      s8v hv, mv, lv;
#pragma unroll
      for (int e = 0; e < 8; ++e) {
        short h, m, lo; split3(tl[pl2][cq + grp * 8 + e], h, m, lo);
        hv[e] = h; mv[e] = m; lv[e] = lo;
      }
      *(s8v*)(out + oo + grp * 8) = hv;
      *(s8v*)(out + PLANE + oo + grp * 8) = mv;
      *(s8v*)(out + 2 * PLANE + oo + grp * 8) = lv;
    }
  }
}

// ==================== MFMA conv 3x3 + bias + relu (16x16x32, both towers) ====================
// blockIdx.z: tower = z>>2 (0:cls 1:bbox), n = z&3. Serial fallback launches z-dim 4.
// act_s sigma-swizzle: physical slot = q*180 + (pos + 2q) % 180 -> q-groups at bank
// offsets {0,24,16,8} dwords, killing the q0/q2,q1/q3 4-way bank aliasing (8 extra
// cyc per b128 read, SQ_LDS_BANK_CONFLICT=2.875e7/dispatch at r7). DMA dest stays
// linear (rule 21): the permutation is applied to the per-lane GLOBAL source.
__global__ __launch_bounds__(256, 2) void conv_all_k(const short* __restrict__ in0,
                                                     const short* __restrict__ in1,
                                                     const short* __restrict__ wt0,
                                                     const short* __restrict__ wt1,
                                                     const float* __restrict__ bias0,
                                                     const float* __restrict__ bias1,
                                                     short* __restrict__ out0,
                                                     short* __restrict__ out1, Geo g)
{
  __shared__ short act_s[2 * 3 * 768 * 8];  // [buf][plane][768 slots][8ci] = 73.7 KB

  const int t = threadIdx.x;
  const int lane = t & 63, wave = t >> 6;
  const int wcol = wave & 1, wko = wave >> 1;
  const int tower = blockIdx.z >> 2;
  const int n = blockIdx.z & 3;
  const short* in   = tower ? in1 : in0;
  const short* wtL  = tower ? wt1 : wt0;
  const float* bias = tower ? bias1 : bias0;
  short* out        = tower ? out1 : out0;
  const int ko0 = blockIdx.y * 128;
  int bx = blockIdx.x;
  int l = 0; while (l < 4 && bx >= g.tp[l + 1]) ++l;
  const int H = g.Ha[l], W = g.Wa[l], PW = g.PWa[l], PHW = g.PHWa[l];
  const int lt = bx - g.tp[l];
  const int TX = g.TXa[l];
  const int ty = lt / TX, tx = lt - ty * TX;
  const int R0 = ty * 8, C0 = tx * 16;
  const size_t bi = ((size_t)g.phwOff[l] * 4 + (size_t)n * PHW) * 256;
  const short* inN = in + bi;
  short* outN = out + bi;

  const int r = lane & 15, q = lane >> 4;
  const int cb = wcol * 8;
  const short* wlane = wtL + (size_t)q * 2048 + (size_t)(ko0 + wko * 64 + r) * 8;

  // per-thread GLOBAL source offsets for staging: physical slot j holds logical
  // slot (qq, (j%180 - 2*qq) mod 180)  [sigma inverse applied to the source]
  int soff[3];
#pragma unroll
  for (int k = 0; k < 3; ++k) {
    int j = t + k * 256; if (j > 719) j = 719;
    int qq = j / 180, ppos = j - qq * 180;
    int lpos = ppos - 2 * qq; if (lpos < 0) lpos += 180;
    int row = lpos / 18, col = lpos - row * 18;
    int prow = R0 + row; if (prow > H + 1) prow = H + 1;
    int pcol = C0 + col; if (pcol > W + 1) pcol = W + 1;
    soff[k] = (prow * PW + pcol) * 256 + qq * 8;
  }

  f4v acc[4][4];
#pragma unroll
  for (int mi = 0; mi < 4; ++mi)
#pragma unroll
    for (int ni = 0; ni < 4; ++ni) { f4v z = {0.f, 0.f, 0.f, 0.f}; acc[mi][ni] = z; }

  auto stage = [&](int cc, int buf) {
#pragma unroll
    for (int k = 0; k < 3; ++k)
#pragma unroll
      for (int p = 0; p < 3; ++p) {
        const short* src = inN + (size_t)p * PLANE + (size_t)(soff[k] + cc * 32);
        short* dst = &act_s[(size_t)buf * 18432 + (size_t)p * 6144 + (size_t)(t + k * 256) * 8];
#if __has_builtin(__builtin_amdgcn_global_load_lds)
        __builtin_amdgcn_global_load_lds((const __attribute__((address_space(1))) void*)src,
                                         (__attribute__((address_space(3))) void*)dst, 16, 0, 0);
#else
        *(s8v*)dst = *(const s8v*)src;
#endif
      }
  };

  auto loadB = [&](s8v (&bf)[3][4], int cc2, int tap2) {
    const short* base = wlane + (size_t)(tap2 * 8 + cc2) * 8192;
#pragma unroll
    for (int p = 0; p < 3; ++p)
#pragma unroll
      for (int ni = 0; ni < 4; ++ni)
        bf[p][ni] = *(const s8v*)(base + (size_t)p * 589824 + ni * 128);
  };

  auto runTap = [&](const s8v (&bf)[3][4], int dy, int dx, int buf) {
    s8v afr[3][4];
    const int sbase = buf * 18432;
#pragma unroll
    for (int mi = 0; mi < 4; ++mi) {
      // sigma-swizzled read: sl = q*180 + (pos + 2q) mod 180
      int lp = (2 * mi + (r >> 3) + dy) * 18 + (cb + (r & 7) + dx) + 2 * q;
      if (lp >= 180) lp -= 180;
      int sl = q * 180 + lp;
      afr[0][mi] = *(const s8v*)&act_s[sbase + sl * 8];
      afr[1][mi] = *(const s8v*)&act_s[sbase + 6144 + sl * 8];
      afr[2][mi] = *(const s8v*)&act_s[sbase + 12288 + sl * 8];
    }
    const int PA[6] = {0, 0, 1, 1, 0, 2};
    const int PB[6] = {0, 1, 0, 1, 2, 0};
    __builtin_amdgcn_s_setprio(1);
#pragma unroll
    for (int pp = 0; pp < 6; ++pp) {
#pragma unroll
      for (int mi = 0; mi < 4; ++mi)
#pragma unroll
        for (int ni = 0; ni < 4; ++ni)
          acc[mi][ni] = __builtin_amdgcn_mfma_f32_16x16x32_bf16(
              afr[PA[pp]][mi], bf[PB[pp]][ni], acc[mi][ni], 0, 0, 0);
    }
    __builtin_amdgcn_s_setprio(0);
  };

  s8v bfrA[3][4], bfrB[3][4];
  stage(0, 0);
  loadB(bfrA, 0, 0);
  __syncthreads();            // compiler drains vmcnt(0) before s_barrier

  int cur = 0;
  for (int cc = 0; cc < 8; ++cc) {
    if (cc < 7) stage(cc + 1, cur ^ 1);   // DMA hides under the 864 MFMAs below
#pragma unroll
    for (int tap = 0; tap < 9; ++tap) {
      const int dy = tap / 3, dx = tap - dy * 3;
      if (tap < 8) {
        if (tap & 1) loadB(bfrA, cc, tap + 1); else loadB(bfrB, cc, tap + 1);
      } else if (cc < 7) {
        loadB(bfrB, cc + 1, 0);
      }
      if (tap & 1) runTap(bfrB, dy, dx, cur); else runTap(bfrA, dy, dx, cur);
    }
    if (cc < 7) {
#pragma unroll
      for (int p = 0; p < 3; ++p)
#pragma unroll
        for (int ni = 0; ni < 4; ++ni) bfrA[p][ni] = bfrB[p][ni];
    }
    __syncthreads();          // vmcnt drain (DMA landed) + all waves done with act_s[cur]
    cur ^= 1;
  }

  // epilogue: bias + relu + split3, store 3 bf16 planes (masked)
#pragma unroll
  for (int mi = 0; mi < 4; ++mi) {
#pragma unroll
    for (int ni = 0; ni < 4; ++ni) {
      int ko = ko0 + wko * 64 + ni * 16 + r;
      float bv = bias[ko];
#pragma unroll
      for (int reg = 0; reg < 4; ++reg) {
        int rm = q * 4 + reg;
        int orow = R0 + 2 * mi + (rm >> 3);
        int ocol = C0 + cb + (rm & 7);
        if (orow < H && ocol < W) {
          float vv = fmaxf(acc[mi][ni][reg] + bv, 0.f);
          short h, m, lo; split3(vv, h, m, lo);
          size_t oo = ((size_t)(orow + 1) * PW + (ocol + 1)) * 256 + ko;
          outN[oo] = h; outN[PLANE + oo] = m; outN[2 * PLANE + oo] = lo;
        }
      }
    }
  }
}

// ==================== cls head (all levels): 1x1x80 + sigmoid ====================
__global__ __launch_bounds__(256) void cls_head_k(const short* __restrict__ act,
                                                  const float* __restrict__ wcls,
                                                  const float* __restrict__ bcls,
                                                  float* __restrict__ score, Geo g)
{
  __shared__ int   p2s[64];
  __shared__ float as_[64][69];
  __shared__ float ws_[64][84];
  const int t = threadIdx.x;
  const int n = blockIdx.y;
  int bx = blockIdx.x;
  int l = 0; while (l < 4 && bx >= g.pb[l + 1]) ++l;
  const int H = g.Ha[l], W = g.Wa[l], PW = g.PWa[l], PHW = g.PHWa[l], HW = H * W;
  const int P0 = (bx - g.pb[l]) * 64;
  if (t < 64) {
    int p = P0 + t; if (p >= HW) p = HW - 1;
    int y = p / W, x = p - y * W;
    p2s[t] = (y + 1) * PW + x + 1;
  }
  __syncthreads();
  float accv[4][5];
#pragma unroll
  for (int i = 0; i < 4; ++i)
#pragma unroll
    for (int j = 0; j < 5; ++j) accv[i][j] = 0.f;

  const short* actN = act + ((size_t)g.phwOff[l] * 4 + (size_t)n * PHW) * 256;
  const int pg = t >> 4, cg = t & 15;

  for (int c0 = 0; c0 < 256; c0 += 64) {
    for (int i = t; i < 1024; i += 256) {
      int pos = i >> 4, c4 = i & 15;
      size_t o = (size_t)p2s[pos] * 256 + c0 + c4 * 4;
      s4v hv = *(const s4v*)(actN + o);
      s4v mv = *(const s4v*)(actN + PLANE + o);
      s4v lv = *(const s4v*)(actN + 2 * PLANE + o);
      float* dst = &as_[pos][c4 * 4];
#pragma unroll
      for (int e = 0; e < 4; ++e) dst[e] = b2f(hv[e]) + b2f(mv[e]) + b2f(lv[e]);
    }
    for (int i = t; i < 1280; i += 256) {
      int c = i >> 4, c4 = i & 15;
      float4 v = *(const float4*)(wcls + (size_t)c * 256 + c0 + c4 * 4);
      ws_[c4 * 4 + 0][c] = v.x; ws_[c4 * 4 + 1][c] = v.y;
      ws_[c4 * 4 + 2][c] = v.z; ws_[c4 * 4 + 3][c] = v.w;
    }
    __syncthreads();
#pragma unroll 8
    for (int ci = 0; ci < 64; ++ci) {
#pragma unroll
      for (int i = 0; i < 4; ++i) {
        float a = as_[pg * 4 + i][ci];
#pragma unroll
        for (int j = 0; j < 5; ++j)
          accv[i][j] = fmaf(a, ws_[ci][cg * 5 + j], accv[i][j]);
      }
    }
    __syncthreads();
  }
  float* sB = score + ((size_t)g.hwOff[l] * 4 + (size_t)n * HW) * 80;
#pragma unroll
  for (int i = 0; i < 4; ++i) {
    int p = P0 + pg * 4 + i;
    if (p >= HW) continue;
#pragma unroll
    for (int j = 0; j < 5; ++j) {
      int c = cg * 5 + j;
      sB[(size_t)p * 80 + c] = sigf(accv[i][j] + bcls[c]);
    }
  }
}

// ==================== box head (all levels) ====================
__global__ __launch_bounds__(256) void box_head_k(const short* __restrict__ act,
                                                  const float* __restrict__ wbox,
                                                  const float* __restrict__ bb,
                                                  const float* __restrict__ wctr,
                                                  const float* __restrict__ bc,
                                                  const float* __restrict__ scales,
                                                  float* __restrict__ score,
                                                  float* __restrict__ deltas, Geo g)
{
  int n = blockIdx.y;
  int bx = blockIdx.x;
  int l = 0; while (l < 4 && bx >= g.bb[l + 1]) ++l;
  const int H = g.Ha[l], W = g.Wa[l], PW = g.PWa[l], PHW = g.PHWa[l], HW = H * W;
  int p = (bx - g.bb[l]) * 256 + threadIdx.x;
  if (p >= HW) return;
  int y = p / W, x = p - y * W;
  const short* a = act + ((size_t)g.phwOff[l] * 4 + (size_t)n * PHW + (size_t)(y + 1) * PW + x + 1) * 256;
  float d0 = 0, d1 = 0, d2 = 0, d3 = 0, ct = 0;
  for (int gI = 0; gI < 32; ++gI) {
    s8v hv = *(const s8v*)(a + gI * 8);
    s8v mv = *(const s8v*)(a + PLANE + gI * 8);
    s8v lv = *(const s8v*)(a + 2 * PLANE + gI * 8);
#pragma unroll
    for (int e = 0; e < 8; ++e) {
      float av = b2f(hv[e]) + b2f(mv[e]) + b2f(lv[e]);
      int c = gI * 8 + e;
      d0 = fmaf(av, wbox[c], d0);
      d1 = fmaf(av, wbox[256 + c], d1);
      d2 = fmaf(av, wbox[512 + c], d2);
      d3 = fmaf(av, wbox[768 + c], d3);
      ct = fmaf(av, wctr[c], ct);
    }
  }
  float sl = scales[l];
  float* dd = deltas + ((size_t)g.hwOff[l] * 4 + (size_t)n * HW + p) * 4;
  dd[0] = sl * (d0 + bb[0]); dd[1] = sl * (d1 + bb[1]);
  dd[2] = sl * (d2 + bb[2]); dd[3] = sl * (d3 + bb[3]);
  float sct = sigf(ct + bc[0]);
  float* sp = score + ((size_t)g.hwOff[l] * 4 + (size_t)n * HW + p) * 80;
#pragma unroll
  for (int i = 0; i < 20; ++i) {
    float4 v = ((float4*)sp)[i];
    v.x *= sct; v.y *= sct; v.z *= sct; v.w *= sct;
    v.x = (v.x > 0.05f) ? v.x : 0.f;
    v.y = (v.y > 0.05f) ? v.y : 0.f;
    v.z = (v.z > 0.05f) ? v.z : 0.f;
    v.w = (v.w > 0.05f) ? v.w : 0.f;
    ((float4*)sp)[i] = v;
  }
}

// ==================== exact top-1000: 3-pass bit histogram, 20 (level,image) groups ====================
__global__ __launch_bounds__(256) void hist_k(const float* __restrict__ score,
                                              const unsigned* __restrict__ thr,
                                              unsigned* __restrict__ hist, int phase, Geo g)
{
  const int grp = blockIdx.y;
  const int l = grp >> 2, n = grp & 3;
  const int HW = g.Ha[l] * g.Wa[l];
  const int M = HW * 80;
  const float* s = score + ((size_t)g.hwOff[l] * 4 + (size_t)n * HW) * 80;
  unsigned* h = hist + grp * 2048;
  const unsigned* tr = thr + grp * 8;
  __shared__ unsigned lh[2048];
  for (int i = threadIdx.x; i < 2048; i += 256) lh[i] = 0u;
  __syncthreads();
  unsigned B1 = 0, pref = 0;
  if (phase == 1) B1 = tr[0];
  if (phase == 2) pref = (tr[0] << 11) | tr[1];
  for (int idx = blockIdx.x * 256 + threadIdx.x; idx < M; idx += gridDim.x * 256) {
    float v = s[idx];
    if (v > 0.f) {
      unsigned b = __float_as_uint(v);
      if (phase == 0) atomicAdd(&lh[b >> 20], 1u);
      else if (phase == 1) { if ((b >> 20) == B1) atomicAdd(&lh[(b >> 9) & 0x7FFu], 1u); }
      else { if ((b >> 9) == pref) atomicAdd(&lh[b & 0x1FFu], 1u); }
    }
  }
  __syncthreads();
  for (int i = threadIdx.x; i < 2048; i += 256) { unsigned v = lh[i]; if (v) atomicAdd(&h[i], v); }
}

__global__ __launch_bounds__(256) void scan_k(unsigned* __restrict__ hist,
                                              unsigned* __restrict__ thr, int phase)
{
  const int grp = blockIdx.x, t = threadIdx.x;
  unsigned* h  = hist + grp * 2048;
  unsigned* tr = thr + grp * 8;
  const int nb = (phase == 2) ? 512 : 2048;
  const int PB = nb / 256;
  unsigned target = 1000u;
  bool dead = false;
  if (phase >= 1) {
    target = 1000u - tr[2];
    if (tr[0] == 0xFFFFFFFFu) dead = true;
    if (phase == 2 && tr[1] == 0xFFFFFFFFu) dead = true;
  }
  __shared__ unsigned ps[256];
  __shared__ unsigned s_tot;
  const int hi = nb - t * PB;
  unsigned lsum = 0;
  for (int k = 0; k < PB; ++k) lsum += h[hi - 1 - k];
  ps[t] = lsum;
  __syncthreads();
  if (t == 0) {
    unsigned cum = 0;
    for (int i = 0; i < 256; ++i) { unsigned tmp = ps[i]; ps[i] = cum; cum += tmp; }
    s_tot = cum;
  }
  __syncthreads();
  unsigned exc = ps[t], tot = s_tot;
  if (!dead && tot >= target) {
    if (exc < target && exc + lsum >= target) {
      unsigned cum = exc; int bf = 0; unsigned above = 0;
      for (int k = 0; k < PB; ++k) {
        int bidx = hi - 1 - k;
        unsigned c = h[bidx];
        if (cum < target && cum + c >= target) { bf = bidx; above = cum; }
        cum += c;
      }
      if (phase == 0)      { tr[0] = (unsigned)bf; tr[2] = above; }
      else if (phase == 1) { tr[1] = (unsigned)bf; tr[2] = tr[2] + above; }
      else {
        unsigned T = (tr[0] << 20) | (tr[1] << 9) | (unsigned)bf;
        tr[3] = T; tr[4] = target - above;
      }
    }
  } else if (t == 0) {
    if (phase == 0)      { tr[0] = 0xFFFFFFFFu; tr[2] = 0u; }
    else if (phase == 1) { tr[1] = 0xFFFFFFFFu; }
    else                 { tr[3] = 0u; tr[4] = 0u; }
  }
  if (phase == 2 && t == 0) { tr[5] = 0u; tr[6] = 0u; }
}

// ==================== select + decode ====================
__global__ __launch_bounds__(256) void select_k(const float* __restrict__ score,
                                                const float* __restrict__ deltas,
                                                unsigned* __restrict__ thr,
                                                float* __restrict__ cbox, float* __restrict__ csc,
                                                float* __restrict__ ccls, float* __restrict__ cgid,
                                                Geo g)
{
  const int grp = blockIdx.y;
  const int l = grp >> 2, n = grp & 3;
  const int W = g.Wa[l];
  const int HW = g.Ha[l] * W;
  const int M = HW * 80;
  const float stride_ = (float)(8 << l);
  const float* s = score + ((size_t)g.hwOff[l] * 4 + (size_t)n * HW) * 80;
  const float* dBase = deltas + ((size_t)g.hwOff[l] * 4 + (size_t)n * HW) * 4;
  unsigned* tr = thr + grp * 8;
  const unsigned T = tr[3], need = tr[4];
  for (int idx = blockIdx.x * 256 + threadIdx.x; idx < M; idx += gridDim.x * 256) {
    float v = s[idx];
    if (!(v > 0.f)) continue;
    unsigned b = __float_as_uint(v);
    int slot = -1;
    if (b > T) slot = (int)atomicAdd(&tr[5], 1u);
    else if (b == T) {
      unsigned e = atomicAdd(&tr[6], 1u);
      if (e < need) slot = (int)(1000u - need + e);
    }
    if (slot < 0) continue;
    int p = idx / 80, c = idx - p * 80;
    int y = p / W, x = p - y * W;
    const float* d = dBase + (size_t)p * 4;
    float sz  = 8.f * stride_;
    float acx = ((float)x + 0.5f) * stride_;
    float acy = ((float)y + 0.5f) * stride_;
    float dx = d[0] / 10.f, dy = d[1] / 10.f;
    float dw = fminf(d[2] / 5.f, SCALE_CLAMP);
    float dh = fminf(d[3] / 5.f, SCALE_CLAMP);
    float pcx = dx * sz + acx;
    float pcy = dy * sz + acy;
    float pw = expf(dw) * sz;
    float ph = expf(dh) * sz;
    float x1 = pcx - 0.5f * pw, y1_ = pcy - 0.5f * ph;
    float x2 = pcx + 0.5f * pw, y2_ = pcy + 0.5f * ph;
    x1  = fminf(fmaxf(x1, 0.f),  IMG_SIZE);
    y1_ = fminf(fmaxf(y1_, 0.f), IMG_SIZE);
    x2  = fminf(fmaxf(x2, 0.f),  IMG_SIZE);
    y2_ = fminf(fmaxf(y2_, 0.f), IMG_SIZE);
    int cslot = n * 5000 + l * 1000 + slot;
    ((float4*)cbox)[cslot] = make_float4(x1, y1_, x2, y2_);
    csc[cslot]  = sqrtf(v);
    ccls[cslot] = (float)c;
    cgid[cslot] = (float)(((unsigned)l << 20) | (unsigned)idx);
  }
}

// ==================== class-aware greedy NMS ====================
__global__ __launch_bounds__(256) void nms_k(const float* __restrict__ cbox,
                                             const float* __restrict__ csc,
                                             const float* __restrict__ ccls,
                                             const float* __restrict__ cgid,
                                             float* __restrict__ outp)
{
  const int n = blockIdx.x, t = threadIdx.x;
  float sc[20], cl[20], gid[20], bx[20][4];
#pragma unroll
  for (int j = 0; j < 20; ++j) {
    int gidx = j * 256 + t;
    if (gidx < 5000) {
      sc[j] = csc[n * 5000 + gidx];
      float4 b = ((const float4*)cbox)[n * 5000 + gidx];
      bx[j][0] = b.x; bx[j][1] = b.y; bx[j][2] = b.z; bx[j][3] = b.w;
      cl[j]  = ccls[n * 5000 + gidx];
      gid[j] = cgid[n * 5000 + gidx];
    } else { sc[j] = -2.f; bx[j][0] = bx[j][1] = bx[j][2] = bx[j][3] = 0.f; cl[j] = 0.f; gid[j] = 1e9f; }
  }
  __shared__ float rv[4]; __shared__ int rg[4]; __shared__ float rgid[4];
  __shared__ float sbox[4]; __shared__ float scls; __shared__ float sval; __shared__ int sgi;

  for (int it = 0; it < 100; ++it) {
    float bv = -3.f; int bg = 0; float bgid = 2e9f;
#pragma unroll
    for (int j = 0; j < 20; ++j) {
      bool better = (sc[j] > bv) || (sc[j] == bv && gid[j] < bgid);
      if (better) { bv = sc[j]; bg = j * 256 + t; bgid = gid[j]; }
    }
    for (int off = 32; off; off >>= 1) {
      float ov = __shfl_xor(bv, off);
      int   og = __shfl_xor(bg, off);
      float oi = __shfl_xor(bgid, off);
      bool better = (ov > bv) || (ov == bv && oi < bgid);
      if (better) { bv = ov; bg = og; bgid = oi; }
    }
    int wid = t >> 6;
    if ((t & 63) == 0) { rv[wid] = bv; rg[wid] = bg; rgid[wid] = bgid; }
    __syncthreads();
    if (t == 0) {
      float fv = rv[0]; int fg = rg[0]; float fi = rgid[0];
      for (int w = 1; w < 4; ++w) {
        bool better = (rv[w] > fv) || (rv[w] == fv && rgid[w] < fi);
        if (better) { fv = rv[w]; fg = rg[w]; fi = rgid[w]; }
      }
      sval = fv; sgi = fg;
    }
    __syncthreads();
    float best_v = sval; int best_g = sgi;
    if (t == (best_g & 255)) {
      int j = best_g >> 8;
      sbox[0] = bx[j][0]; sbox[1] = bx[j][1]; sbox[2] = bx[j][2]; sbox[3] = bx[j][3];
      scls = cl[j];
    }
    __syncthreads();
    bool valid = best_v > 0.f;
    if (t == 0) {
      int base = n * 100 + it;
      outp[base * 4 + 0] = valid ? sbox[0] : 0.f;
      outp[base * 4 + 1] = valid ? sbox[1] : 0.f;
      outp[base * 4 + 2] = valid ? sbox[2] : 0.f;
      outp[base * 4 + 3] = valid ? sbox[3] : 0.f;
      outp[1600 + base] = valid ? best_v : 0.f;
      outp[2000 + base] = valid ? scls : -1.f;
    }
    float off_ = scls * (2.f * IMG_SIZE);
    float e0 = sbox[0] + off_, e1 = sbox[1] + off_, e2 = sbox[2] + off_, e3 = sbox[3] + off_;
    float a1 = (e2 - e0) * (e3 - e1);
#pragma unroll
    for (int j = 0; j < 20; ++j) {
      float o_ = cl[j] * (2.f * IMG_SIZE);
      float f0 = bx[j][0] + o_, f1 = bx[j][1] + o_, f2 = bx[j][2] + o_, f3 = bx[j][3] + o_;
      float xx1 = fmaxf(e0, f0), yy1 = fmaxf(e1, f1);
      float xx2 = fminf(e2, f2), yy2 = fminf(e3, f3);
      float inter = fmaxf(xx2 - xx1, 0.f) * fmaxf(yy2 - yy1, 0.f);
      float a2 = (f2 - f0) * (f3 - f1);
      float iou = inter / (a1 + a2 - inter + 1e-9f);
      if (iou > 0.6f) sc[j] = -1.f;
      if ((j * 256 + t) == best_g) sc[j] = -1.f;
    }
    __syncthreads();
  }
}

// ==================== host ====================
extern "C" void kernel_launch(void* const* d_in, const int* in_sizes, int n_in,
                              void* d_out, int out_size, void* d_ws, size_t ws_size,
                              hipStream_t stream)
{
  (void)in_sizes; (void)n_in; (void)out_size;
  const float* p3 = (const float*)d_in[0];
  const float* p4 = (const float*)d_in[1];
  const float* p5 = (const float*)d_in[2];
  const float* p6 = (const float*)d_in[3];
  const float* p7 = (const float*)d_in[4];
  const float* cls_tw  = (const float*)d_in[5];
  const float* cls_tb  = (const float*)d_in[6];
  const float* bbox_tw = (const float*)d_in[7];
  const float* bbox_tb = (const float*)d_in[8];
  const float* wcls    = (const float*)d_in[9];
  const float* bcls    = (const float*)d_in[10];
  const float* wbox    = (const float*)d_in[11];
  const float* bbox_b  = (const float*)d_in[12];
  const float* wctr    = (const float*)d_in[13];
  const float* bctr    = (const float*)d_in[14];
  const float* scales  = (const float*)d_in[15];
  float* out = (float*)d_out;

  // geometry
  Geo G;
  const int Hs[5] = {100, 50, 25, 13, 7};
  {
    int tpre = 0, ppre = 0, bpre = 0, phw = 0, hw = 0;
    for (int l = 0; l < 5; ++l) {
      int H = Hs[l], W = Hs[l];
      G.Ha[l] = H; G.Wa[l] = W; G.PWa[l] = W + 2; G.PHWa[l] = (H + 2) * (W + 2);
      G.TXa[l] = (W + 15) / 16;
      int TY = (H + 7) / 8;
      G.tp[l] = tpre;  tpre += G.TXa[l] * TY;
      G.pb[l] = ppre;  ppre += (H * W + 63) / 64;
      G.bb[l] = bpre;  bpre += (H * W + 255) / 256;
      G.phwOff[l] = phw; phw += G.PHWa[l];
      G.hwOff[l]  = hw;  hw  += H * W;
    }
    G.tp[5] = tpre; G.pb[5] = ppre; G.bb[5] = bpre;
  }
  const int nTiles = G.tp[5];   // 130
  const int nPrep  = G.pb[5];   // 211
  const int nBoxB  = G.bb[5];   // 55
  const int sumHW = 13343;
  const size_t scoreBytes  = (size_t)sumHW * 4 * 80 * 4;   // 17.08 MB
  const size_t deltasBytes = (size_t)sumHW * 4 * 4 * 4;    // 0.854 MB

  char* ws = (char*)d_ws;
  size_t off = 0;
  auto alloc = [&](size_t bytes) -> void* {
    off = (off + 255) & ~(size_t)255;
    void* p = ws + off; off += bytes; return p;
  };
  const size_t bufBytes = 3ull * PLANE * 2;   // one split-plane act buffer = 86.9 MB

  // fixed small allocations (both paths)
  short* wt     = (short*)alloc((size_t)8 * 3 * 589824 * 2);   // 28.3 MB
  float* cbox   = (float*)alloc(4ull * 5000 * 4 * 4);
  float* csc    = (float*)alloc(4ull * 5000 * 4);
  float* ccls   = (float*)alloc(4ull * 5000 * 4);
  float* cgid   = (float*)alloc(4ull * 5000 * 4);
  unsigned* hist = (unsigned*)alloc(20ull * 2048 * 4);
  unsigned* thr  = (unsigned*)alloc(20ull * 8 * 4);
  const size_t fixedEnd = off;
  // fused needs 4 act buffers; score/deltas alias buffer A (dead after L3)
  const bool fused = (ws_size >= ((fixedEnd + 255) & ~(size_t)255) + 4 * (bufBytes + 256) + 4096);

  hipMemsetAsync(cbox, 0, 4ull * 5000 * 4 * 4, stream);
  hipMemsetAsync(csc,  0, 4ull * 5000 * 4, stream);
  hipMemsetAsync(ccls, 0, 4ull * 5000 * 4, stream);
  hipMemsetAsync(cgid, 0, 4ull * 5000 * 4, stream);
  hipMemsetAsync(thr,  0, 20ull * 8 * 4, stream);

  wtrans_k<<<1024, 256, 0, stream>>>(cls_tw, bbox_tw, wt);

  const size_t LSTRIDE = 3ull * 589824;  // shorts per conv layer (3 planes)
  float* score;
  float* deltas;
  short* clsFinal = nullptr;
  short* boxFinal = nullptr;

  if (fused) {
    short* P = (short*)alloc(bufBytes);
    short* A = (short*)alloc(bufBytes);
    short* B = (short*)alloc(bufBytes);
    short* C = (short*)alloc(bufBytes);
    score  = (float*)A;                                     // A dead after L3
    deltas = (float*)((char*)A + ((scoreBytes + 255) & ~(size_t)255));
    hipMemsetAsync(P, 0, bufBytes, stream);
    hipMemsetAsync(A, 0, bufBytes, stream);
    hipMemsetAsync(B, 0, bufBytes, stream);
    hipMemsetAsync(C, 0, bufBytes, stream);

    prep_all_k<<<dim3(nPrep, 4), 256, 0, stream>>>(p3, p4, p5, p6, p7, P, G);

    dim3 cg(nTiles, 2, 8);  // z: tower*4 + image
    conv_all_k<<<cg, 256, 0, stream>>>(P, P, wt + 0 * LSTRIDE, wt + 4 * LSTRIDE,
                                       cls_tb + 0 * 256, bbox_tb + 0 * 256, A, B, G);
    conv_all_k<<<cg, 256, 0, stream>>>(A, B, wt + 1 * LSTRIDE, wt + 5 * LSTRIDE,
                                       cls_tb + 1 * 256, bbox_tb + 1 * 256, C, P, G);
    conv_all_k<<<cg, 256, 0, stream>>>(C, P, wt + 2 * LSTRIDE, wt + 6 * LSTRIDE,
                                       cls_tb + 2 * 256, bbox_tb + 2 * 256, A, B, G);
    conv_all_k<<<cg, 256, 0, stream>>>(A, B, wt + 3 * LSTRIDE, wt + 7 * LSTRIDE,
                                       cls_tb + 3 * 256, bbox_tb + 3 * 256, C, P, G);
    clsFinal = C; boxFinal = P;
    cls_head_k<<<dim3(nPrep, 4), 256, 0, stream>>>(clsFinal, wcls, bcls, score, G);
  } else {
    short* A = (short*)alloc(bufBytes);
    short* B = (short*)alloc(bufBytes);
    score  = (float*)alloc(scoreBytes);
    deltas = (float*)alloc(deltasBytes);
    hipMemsetAsync(A, 0, bufBytes, stream);
    hipMemsetAsync(B, 0, bufBytes, stream);
    dim3 cg(nTiles, 2, 4);  // z: image only (tower 0 slots)
    // cls tower: prep->A, A->B->A->B->A
    prep_all_k<<<dim3(nPrep, 4), 256, 0, stream>>>(p3, p4, p5, p6, p7, A, G);
    conv_all_k<<<cg, 256, 0, stream>>>(A, A, wt + 0 * LSTRIDE, wt + 0 * LSTRIDE,
                                       cls_tb + 0 * 256, cls_tb + 0 * 256, B, B, G);
    conv_all_k<<<cg, 256, 0, stream>>>(B, B, wt + 1 * LSTRIDE, wt + 1 * LSTRIDE,
                                       cls_tb + 1 * 256, cls_tb + 1 * 256, A, A, G);
    conv_all_k<<<cg, 256, 0, stream>>>(A, A, wt + 2 * LSTRIDE, wt + 2 * LSTRIDE,
                                       cls_tb + 2 * 256, cls_tb + 2 * 256, B, B, G);
    conv_all_k<<<cg, 256, 0, stream>>>(B, B, wt + 3 * LSTRIDE, wt + 3 * LSTRIDE,
                                       cls_tb + 3 * 256, cls_tb + 3 * 256, A, A, G);
    cls_head_k<<<dim3(nPrep, 4), 256, 0, stream>>>(A, wcls, bcls, score, G);
    // bbox tower: re-prep->B, B->A->B->A->B
    prep_all_k<<<dim3(nPrep, 4), 256, 0, stream>>>(p3, p4, p5, p6, p7, B, G);
    conv_all_k<<<cg, 256, 0, stream>>>(B, B, wt + 4 * LSTRIDE, wt + 4 * LSTRIDE,
                                       bbox_tb + 0 * 256, bbox_tb + 0 * 256, A, A, G);
    conv_all_k<<<cg, 256, 0, stream>>>(A, A, wt + 5 * LSTRIDE, wt + 5 * LSTRIDE,
                                       bbox_tb + 1 * 256, bbox_tb + 1 * 256, B, B, G);
    conv_all_k<<<cg, 256, 0, stream>>>(B, B, wt + 6 * LSTRIDE, wt + 6 * LSTRIDE,
                                       bbox_tb + 2 * 256, bbox_tb + 2 * 256, A, A, G);
    conv_all_k<<<cg, 256, 0, stream>>>(A, A, wt + 7 * LSTRIDE, wt + 7 * LSTRIDE,
                                       bbox_tb + 3 * 256, bbox_tb + 3 * 256, B, B, G);
    boxFinal = B;
  }

  box_head_k<<<dim3(nBoxB, 4), 256, 0, stream>>>(boxFinal, wbox, bbox_b, wctr, bctr, scales,
                                                 score, deltas, G);

  // exact top-1000 per (level, image)
  const int hb = 196;
  for (int phase = 0; phase < 3; ++phase) {
    hipMemsetAsync(hist, 0, 20ull * 2048 * 4, stream);
    hist_k<<<dim3(hb, 20), 256, 0, stream>>>(score, thr, hist, phase, G);
    scan_k<<<20, 256, 0, stream>>>(hist, thr, phase);
  }
  select_k<<<dim3(hb, 20), 256, 0, stream>>>(score, deltas, thr, cbox, csc, ccls, cgid, G);

  nms_k<<<4, 256, 0, stream>>>(cbox, csc, ccls, cgid, out);
}

// Round 9
// 3424.903 us; speedup vs baseline: 1.2466x; 1.0170x over previous
//
#include <hip/hip_runtime.h>
#include <math.h>

typedef short s8v __attribute__((ext_vector_type(8)));
typedef short s4v __attribute__((ext_vector_type(4)));
typedef float f4v __attribute__((ext_vector_type(4)));

__device__ __forceinline__ float sigf(float x) { return 1.f / (1.f + expf(-x)); }
__device__ __forceinline__ float b2f(short v) {
  return __uint_as_float(((unsigned)(unsigned short)v) << 16);
}

#define SCALE_CLAMP 4.135166556742356f
#define IMG_SIZE 800.f
#define PLANE 14482432ull   // shorts per activation plane: sumPHW(14143)*4*256

// 3-way bf16 split (round-to-nearest): x ~= h + m + l, err ~2^-27 |x|
__device__ __forceinline__ void split3(float x, short& h, short& m, short& l) {
  unsigned u = __float_as_uint(x);
  unsigned hb = (u + 0x7FFFu + ((u >> 16) & 1u)) >> 16;
  float hf = __uint_as_float(hb << 16);
  float d1 = x - hf;
  unsigned u1 = __float_as_uint(d1);
  unsigned mb = (u1 + 0x7FFFu + ((u1 >> 16) & 1u)) >> 16;
  float mf = __uint_as_float(mb << 16);
  float d2 = d1 - mf;
  unsigned u2 = __float_as_uint(d2);
  unsigned lb = (u2 + 0x7FFFu + ((u2 >> 16) & 1u)) >> 16;
  h = (short)hb; m = (short)mb; l = (short)lb;
}

struct Geo {
  int tp[6];                 // conv tile prefix per level (4x16 tiles)
  int TXa[5];
  int Ha[5], Wa[5], PWa[5], PHWa[5];
  int phwOff[5];             // PHW prefix
  int hwOff[5];              // HW prefix
  int pb[6];                 // ceil(HW/64) prefix  (prep + cls head)
  int bb[6];                 // ceil(HW/256) prefix (box head)
};

// ==================== weight split+transpose (16x16 layout) ====================
// out layout (bf16 shorts): [layer8][plane3][ (tap*8+cc)*4+q ][ko 256][e 8]
__global__ __launch_bounds__(256) void wtrans_k(const float* __restrict__ cls_tw,
                                                const float* __restrict__ bbox_tw,
                                                short* __restrict__ wt)
{
  const int total = 589824;
  for (int u = blockIdx.x * 256 + threadIdx.x; u < total; u += gridDim.x * 256) {
    int layer = u / 73728;
    int r = u - layer * 73728;
    int tap = r / 8192;  r -= tap * 8192;
    int cc  = r / 1024;  r -= cc * 1024;
    int qq  = r / 256;   int ko = r - qq * 256;
    int cibase = cc * 32 + qq * 8;
    const float* src = (layer < 4) ? (cls_tw + (size_t)layer * 589824)
                                   : (bbox_tw + (size_t)(layer - 4) * 589824);
    s8v hv, mv, lv;
#pragma unroll
    for (int e = 0; e < 8; ++e) {
      float x = src[(size_t)ko * 2304 + (size_t)(cibase + e) * 9 + tap];
      short h, m, l; split3(x, h, m, l);
      hv[e] = h; mv[e] = m; lv[e] = l;
    }
    size_t dbase = (size_t)layer * 1769472 + (((size_t)tap * 8 + cc) * 4 + qq) * 2048 + (size_t)ko * 8;
    *(s8v*)(wt + dbase) = hv;
    *(s8v*)(wt + dbase + 589824) = mv;
    *(s8v*)(wt + dbase + 2 * 589824) = lv;
  }
}

// ==================== NCHW fp32 -> padded split-plane bf16x3 (all levels) ====================
__global__ __launch_bounds__(256) void prep_all_k(const float* __restrict__ p3, const float* __restrict__ p4,
                                                  const float* __restrict__ p5, const float* __restrict__ p6,
                                                  const float* __restrict__ p7,
                                                  short* __restrict__ out, Geo g)
{
  __shared__ float tl[64][260];
  int bx = blockIdx.x, t = threadIdx.x, n = blockIdx.y;
  int l = 0; while (l < 4 && bx >= g.pb[l + 1]) ++l;
  const float* in = (l == 0) ? p3 : (l == 1) ? p4 : (l == 2) ? p5 : (l == 3) ? p6 : p7;
  int H = g.Ha[l], W = g.Wa[l], PW = g.PWa[l], PHW = g.PHWa[l], HW = H * W;
  int P0 = (bx - g.pb[l]) * 64;
  const float* inN = in + (size_t)n * HW * 256;
  int sub = t >> 6, pl = t & 63;
  int pos = P0 + pl;
  for (int i = 0; i < 64; ++i) {
    int ci = i * 4 + sub;
    tl[pl][ci] = (pos < HW) ? inN[(size_t)ci * HW + pos] : 0.f;
  }
  __syncthreads();
  int pl2 = t >> 2, cq = (t & 3) * 64;
  int pos2 = P0 + pl2;
  if (pos2 < HW) {
    int y = pos2 / W, x = pos2 - y * W;
    size_t oo = ((size_t)g.phwOff[l] * 4 + (size_t)n * PHW + (size_t)(y + 1) * PW + (x + 1)) * 256 + cq;
#pragma unroll
    for (int grp = 0; grp < 8; ++grp) {
      s8v hv, mv, lv;
#pragma unroll
      for (int e = 0; e < 8; ++e) {
        short h, m, lo; split3(tl[pl2][cq + grp * 8 + e], h, m, lo);
        hv[e] = h; mv[e] = m; lv[e] = lo;
      }
      *(s8v*)(out + oo + grp * 8) = hv;
      *(s8v*)(out + PLANE + oo + grp * 8) = mv;
      *(s8v*)(out + 2 * PLANE + oo + grp * 8) = lv;
    }
  }
}

// ==================== MFMA conv 3x3 + bias + relu (16x16x32, 4x16 tile, 3 wv/SIMD) ====================
// Tile: 4 rows x 16 cols x 128 ko. 4 waves: wcol(2) x wko(2); per wave 4x8 pos x 64 ko,
// acc[2][4] (32 f32). Halo 6x18 = 108 slots/q-group, sigma-swizzled (phys = q*108 +
// (pos+2q)%108 -> q bank bases {0,24,16,8}), planes padded to 448 slots; LDS 42KB
// double-buffered -> 3 blocks/CU. Weights reg-pipelined in ni-halves (48 VGPR live).
// Target: ~140 VGPR total -> 3 waves/SIMD; 1976 blocks/dispatch -> {7,8}/CU tail ~4%.
#define QS   108
#define PSLOT 448
#define PSTR 3584    // shorts per plane (448*8)
#define BSTR 10752   // shorts per buffer (3*PSTR)
__global__ __launch_bounds__(256, 3) void conv_all_k(const short* __restrict__ in0,
                                                     const short* __restrict__ in1,
                                                     const short* __restrict__ wt0,
                                                     const short* __restrict__ wt1,
                                                     const float* __restrict__ bias0,
                                                     const float* __restrict__ bias1,
                                                     short* __restrict__ out0,
                                                     short* __restrict__ out1, Geo g)
{
  __shared__ short act_s[2 * 3 * PSLOT * 8];  // 43008 B

  const int t = threadIdx.x;
  const int lane = t & 63, wave = t >> 6;
  const int wcol = wave & 1, wko = wave >> 1;
  const int tower = blockIdx.z >> 2;
  const int n = blockIdx.z & 3;
  const short* in   = tower ? in1 : in0;
  const short* wtL  = tower ? wt1 : wt0;
  const float* bias = tower ? bias1 : bias0;
  short* out        = tower ? out1 : out0;
  const int ko0 = blockIdx.y * 128;
  int bx = blockIdx.x;
  int l = 0; while (l < 4 && bx >= g.tp[l + 1]) ++l;
  const int H = g.Ha[l], W = g.Wa[l], PW = g.PWa[l], PHW = g.PHWa[l];
  const int lt = bx - g.tp[l];
  const int TX = g.TXa[l];
  const int ty = lt / TX, tx = lt - ty * TX;
  const int R0 = ty * 4, C0 = tx * 16;
  const size_t bi = ((size_t)g.phwOff[l] * 4 + (size_t)n * PHW) * 256;
  const short* inN = in + bi;
  short* outN = out + bi;

  const int r = lane & 15, q = lane >> 4;
  const int cb = wcol * 8;
  const short* wlane = wtL + (size_t)q * 2048 + (size_t)(ko0 + wko * 64 + r) * 8;

  // staging GLOBAL source offsets (sigma-inverse applied to source; dst stays linear)
  int soff[2];
#pragma unroll
  for (int k = 0; k < 2; ++k) {
    int j = t + k * 256;
    int jj = (j < 432) ? j : 431;
    int qq = jj / QS, ppos = jj - qq * QS;
    int lpos = ppos - 2 * qq; if (lpos < 0) lpos += QS;
    int row = lpos / 18, col = lpos - row * 18;
    int prow = R0 + row; if (prow > H + 1) prow = H + 1;
    int pcol = C0 + col; if (pcol > W + 1) pcol = W + 1;
    soff[k] = (prow * PW + pcol) * 256 + qq * 8;
  }

  f4v acc[2][4];
#pragma unroll
  for (int mi = 0; mi < 2; ++mi)
#pragma unroll
    for (int ni = 0; ni < 4; ++ni) { f4v z = {0.f, 0.f, 0.f, 0.f}; acc[mi][ni] = z; }

  auto stage = [&](int cc, int buf) {
#pragma unroll
    for (int k = 0; k < 2; ++k) {
      int j = t + k * 256;
      if (j < 448) {  // wave-uniform: only wave 3 skips k=1
#pragma unroll
        for (int p = 0; p < 3; ++p) {
          const short* src = inN + (size_t)p * PLANE + (size_t)(soff[k] + cc * 32);
          short* dst = &act_s[(size_t)buf * BSTR + (size_t)p * PSTR + (size_t)j * 8];
#if __has_builtin(__builtin_amdgcn_global_load_lds)
          __builtin_amdgcn_global_load_lds((const __attribute__((address_space(1))) void*)src,
                                           (__attribute__((address_space(3))) void*)dst, 16, 0, 0);
#else
          *(s8v*)dst = *(const s8v*)src;
#endif
        }
      }
    }
  };

  // weights: half = ni pair {0,1} or {2,3}; 6 x 16B loads from L2
  auto loadW = [&](s8v (&w)[3][2], int cc2, int tap2, int half) {
    const short* base = wlane + (size_t)(tap2 * 8 + cc2) * 8192 + half * 256;
#pragma unroll
    for (int p = 0; p < 3; ++p)
#pragma unroll
      for (int k = 0; k < 2; ++k)
        w[p][k] = *(const s8v*)(base + (size_t)p * 589824 + k * 128);
  };

  auto loadA = [&](s8v (&af)[3][2], int dy, int dx, int buf) {
    const int sbase = buf * BSTR;
#pragma unroll
    for (int mi = 0; mi < 2; ++mi) {
      int lp = (2 * mi + (r >> 3) + dy) * 18 + (cb + (r & 7) + dx) + 2 * q;
      if (lp >= QS) lp -= QS;
      int sl = q * QS + lp;
      af[0][mi] = *(const s8v*)&act_s[sbase + sl * 8];
      af[1][mi] = *(const s8v*)&act_s[sbase + PSTR + sl * 8];
      af[2][mi] = *(const s8v*)&act_s[sbase + 2 * PSTR + sl * 8];
    }
  };

  auto runHalf = [&](const s8v (&w)[3][2], const s8v (&af)[3][2], int half) {
    const int PA[6] = {0, 0, 1, 1, 0, 2};
    const int PB[6] = {0, 1, 0, 1, 2, 0};
    __builtin_amdgcn_s_setprio(1);
#pragma unroll
    for (int pp = 0; pp < 6; ++pp)
#pragma unroll
      for (int mi = 0; mi < 2; ++mi)
#pragma unroll
        for (int k = 0; k < 2; ++k)
          acc[mi][half * 2 + k] = __builtin_amdgcn_mfma_f32_16x16x32_bf16(
              af[PA[pp]][mi], w[PB[pp]][k], acc[mi][half * 2 + k], 0, 0, 0);
    __builtin_amdgcn_s_setprio(0);
  };

  s8v wH0[3][2], wH1[3][2], afr[3][2];
  stage(0, 0);
  loadW(wH0, 0, 0, 0);
  __syncthreads();            // vmcnt(0) drained before barrier

  int cur = 0;
  for (int cc = 0; cc < 8; ++cc) {
    if (cc < 7) stage(cc + 1, cur ^ 1);   // DMA hides under this cc's 432 MFMAs
#pragma unroll
    for (int tap = 0; tap < 9; ++tap) {
      const int dy = tap / 3, dx = tap - dy * 3;
      loadW(wH1, cc, tap, 1);             // issue half1 (current tap)
      loadA(afr, dy, dx, cur);
      runHalf(wH0, afr, 0);               // half0 (prefetched last phase)
      int ntap = tap + 1, ncc = cc;
      if (ntap == 9) { ntap = 0; ++ncc; }
      if (ncc < 8) loadW(wH0, ncc, ntap, 0);  // issue next tap's half0
      runHalf(wH1, afr, 1);
    }
    __syncthreads();          // vmcnt drain (DMA landed) + all waves done with act_s[cur]
    cur ^= 1;
  }

  // epilogue: bias + relu + split3, store 3 bf16 planes (masked)
#pragma unroll
  for (int mi = 0; mi < 2; ++mi) {
#pragma unroll
    for (int ni = 0; ni < 4; ++ni) {
      int ko = ko0 + wko * 64 + ni * 16 + r;
      float bv = bias[ko];
#pragma unroll
      for (int reg = 0; reg < 4; ++reg) {
        int rm = q * 4 + reg;
        int orow = R0 + 2 * mi + (rm >> 3);
        int ocol = C0 + cb + (rm & 7);
        if (orow < H && ocol < W) {
          float vv = fmaxf(acc[mi][ni][reg] + bv, 0.f);
          short h, m, lo; split3(vv, h, m, lo);
          size_t oo = ((size_t)(orow + 1) * PW + (ocol + 1)) * 256 + ko;
          outN[oo] = h; outN[PLANE + oo] = m; outN[2 * PLANE + oo] = lo;
        }
      }
    }
  }
}

// ==================== cls head (all levels): 1x1x80 + sigmoid ====================
__global__ __launch_bounds__(256) void cls_head_k(const short* __restrict__ act,
                                                  const float* __restrict__ wcls,
                                                  const float* __restrict__ bcls,
                                                  float* __restrict__ score, Geo g)
{
  __shared__ int   p2s[64];
  __shared__ float as_[64][69];
  __shared__ float ws_[64][84];
  const int t = threadIdx.x;
  const int n = blockIdx.y;
  int bx = blockIdx.x;
  int l = 0; while (l < 4 && bx >= g.pb[l + 1]) ++l;
  const int H = g.Ha[l], W = g.Wa[l], PW = g.PWa[l], PHW = g.PHWa[l], HW = H * W;
  const int P0 = (bx - g.pb[l]) * 64;
  if (t < 64) {
    int p = P0 + t; if (p >= HW) p = HW - 1;
    int y = p / W, x = p - y * W;
    p2s[t] = (y + 1) * PW + x + 1;
  }
  __syncthreads();
  float accv[4][5];
#pragma unroll
  for (int i = 0; i < 4; ++i)
#pragma unroll
    for (int j = 0; j < 5; ++j) accv[i][j] = 0.f;

  const short* actN = act + ((size_t)g.phwOff[l] * 4 + (size_t)n * PHW) * 256;
  const int pg = t >> 4, cg = t & 15;

  for (int c0 = 0; c0 < 256; c0 += 64) {
    for (int i = t; i < 1024; i += 256) {
      int pos = i >> 4, c4 = i & 15;
      size_t o = (size_t)p2s[pos] * 256 + c0 + c4 * 4;
      s4v hv = *(const s4v*)(actN + o);
      s4v mv = *(const s4v*)(actN + PLANE + o);
      s4v lv = *(const s4v*)(actN + 2 * PLANE + o);
      float* dst = &as_[pos][c4 * 4];
#pragma unroll
      for (int e = 0; e < 4; ++e) dst[e] = b2f(hv[e]) + b2f(mv[e]) + b2f(lv[e]);
    }
    for (int i = t; i < 1280; i += 256) {
      int c = i >> 4, c4 = i & 15;
      float4 v = *(const float4*)(wcls + (size_t)c * 256 + c0 + c4 * 4);
      ws_[c4 * 4 + 0][c] = v.x; ws_[c4 * 4 + 1][c] = v.y;
      ws_[c4 * 4 + 2][c] = v.z; ws_[c4 * 4 + 3][c] = v.w;
    }
    __syncthreads();
#pragma unroll 8
    for (int ci = 0; ci < 64; ++ci) {
#pragma unroll
      for (int i = 0; i < 4; ++i) {
        float a = as_[pg * 4 + i][ci];
#pragma unroll
        for (int j = 0; j < 5; ++j)
          accv[i][j] = fmaf(a, ws_[ci][cg * 5 + j], accv[i][j]);
      }
    }
    __syncthreads();
  }
  float* sB = score + ((size_t)g.hwOff[l] * 4 + (size_t)n * HW) * 80;
#pragma unroll
  for (int i = 0; i < 4; ++i) {
    int p = P0 + pg * 4 + i;
    if (p >= HW) continue;
#pragma unroll
    for (int j = 0; j < 5; ++j) {
      int c = cg * 5 + j;
      sB[(size_t)p * 80 + c] = sigf(accv[i][j] + bcls[c]);
    }
  }
}

// ==================== box head (all levels) ====================
__global__ __launch_bounds__(256) void box_head_k(const short* __restrict__ act,
                                                  const float* __restrict__ wbox,
                                                  const float* __restrict__ bb,
                                                  const float* __restrict__ wctr,
                                                  const float* __restrict__ bc,
                                                  const float* __restrict__ scales,
                                                  float* __restrict__ score,
                                                  float* __restrict__ deltas, Geo g)
{
  int n = blockIdx.y;
  int bx = blockIdx.x;
  int l = 0; while (l < 4 && bx >= g.bb[l + 1]) ++l;
  const int H = g.Ha[l], W = g.Wa[l], PW = g.PWa[l], PHW = g.PHWa[l], HW = H * W;
  int p = (bx - g.bb[l]) * 256 + threadIdx.x;
  if (p >= HW) return;
  int y = p / W, x = p - y * W;
  const short* a = act + ((size_t)g.phwOff[l] * 4 + (size_t)n * PHW + (size_t)(y + 1) * PW + x + 1) * 256;
  float d0 = 0, d1 = 0, d2 = 0, d3 = 0, ct = 0;
  for (int gI = 0; gI < 32; ++gI) {
    s8v hv = *(const s8v*)(a + gI * 8);
    s8v mv = *(const s8v*)(a + PLANE + gI * 8);
    s8v lv = *(const s8v*)(a + 2 * PLANE + gI * 8);
#pragma unroll
    for (int e = 0; e < 8; ++e) {
      float av = b2f(hv[e]) + b2f(mv[e]) + b2f(lv[e]);
      int c = gI * 8 + e;
      d0 = fmaf(av, wbox[c], d0);
      d1 = fmaf(av, wbox[256 + c], d1);
      d2 = fmaf(av, wbox[512 + c], d2);
      d3 = fmaf(av, wbox[768 + c], d3);
      ct = fmaf(av, wctr[c], ct);
    }
  }
  float sl = scales[l];
  float* dd = deltas + ((size_t)g.hwOff[l] * 4 + (size_t)n * HW + p) * 4;
  dd[0] = sl * (d0 + bb[0]); dd[1] = sl * (d1 + bb[1]);
  dd[2] = sl * (d2 + bb[2]); dd[3] = sl * (d3 + bb[3]);
  float sct = sigf(ct + bc[0]);
  float* sp = score + ((size_t)g.hwOff[l] * 4 + (size_t)n * HW + p) * 80;
#pragma unroll
  for (int i = 0; i < 20; ++i) {
    float4 v = ((float4*)sp)[i];
    v.x *= sct; v.y *= sct; v.z *= sct; v.w *= sct;
    v.x = (v.x > 0.05f) ? v.x : 0.f;
    v.y = (v.y > 0.05f) ? v.y : 0.f;
    v.z = (v.z > 0.05f) ? v.z : 0.f;
    v.w = (v.w > 0.05f) ? v.w : 0.f;
    ((float4*)sp)[i] = v;
  }
}

// ==================== exact top-1000: 3-pass bit histogram, 20 (level,image) groups ====================
__global__ __launch_bounds__(256) void hist_k(const float* __restrict__ score,
                                              const unsigned* __restrict__ thr,
                                              unsigned* __restrict__ hist, int phase, Geo g)
{
  const int grp = blockIdx.y;
  const int l = grp >> 2, n = grp & 3;
  const int HW = g.Ha[l] * g.Wa[l];
  const int M = HW * 80;
  const float* s = score + ((size_t)g.hwOff[l] * 4 + (size_t)n * HW) * 80;
  unsigned* h = hist + grp * 2048;
  const unsigned* tr = thr + grp * 8;
  __shared__ unsigned lh[2048];
  for (int i = threadIdx.x; i < 2048; i += 256) lh[i] = 0u;
  __syncthreads();
  unsigned B1 = 0, pref = 0;
  if (phase == 1) B1 = tr[0];
  if (phase == 2) pref = (tr[0] << 11) | tr[1];
  for (int idx = blockIdx.x * 256 + threadIdx.x; idx < M; idx += gridDim.x * 256) {
    float v = s[idx];
    if (v > 0.f) {
      unsigned b = __float_as_uint(v);
      if (phase == 0) atomicAdd(&lh[b >> 20], 1u);
      else if (phase == 1) { if ((b >> 20) == B1) atomicAdd(&lh[(b >> 9) & 0x7FFu], 1u); }
      else { if ((b >> 9) == pref) atomicAdd(&lh[b & 0x1FFu], 1u); }
    }
  }
  __syncthreads();
  for (int i = threadIdx.x; i < 2048; i += 256) { unsigned v = lh[i]; if (v) atomicAdd(&h[i], v); }
}

__global__ __launch_bounds__(256) void scan_k(unsigned* __restrict__ hist,
                                              unsigned* __restrict__ thr, int phase)
{
  const int grp = blockIdx.x, t = threadIdx.x;
  unsigned* h  = hist + grp * 2048;
  unsigned* tr = thr + grp * 8;
  const int nb = (phase == 2) ? 512 : 2048;
  const int PB = nb / 256;
  unsigned target = 1000u;
  bool dead = false;
  if (phase >= 1) {
    target = 1000u - tr[2];
    if (tr[0] == 0xFFFFFFFFu) dead = true;
    if (phase == 2 && tr[1] == 0xFFFFFFFFu) dead = true;
  }
  __shared__ unsigned ps[256];
  __shared__ unsigned s_tot;
  const int hi = nb - t * PB;
  unsigned lsum = 0;
  for (int k = 0; k < PB; ++k) lsum += h[hi - 1 - k];
  ps[t] = lsum;
  __syncthreads();
  if (t == 0) {
    unsigned cum = 0;
    for (int i = 0; i < 256; ++i) { unsigned tmp = ps[i]; ps[i] = cum; cum += tmp; }
    s_tot = cum;
  }
  __syncthreads();
  unsigned exc = ps[t], tot = s_tot;
  if (!dead && tot >= target) {
    if (exc < target && exc + lsum >= target) {
      unsigned cum = exc; int bf = 0; unsigned above = 0;
      for (int k = 0; k < PB; ++k) {
        int bidx = hi - 1 - k;
        unsigned c = h[bidx];
        if (cum < target && cum + c >= target) { bf = bidx; above = cum; }
        cum += c;
      }
      if (phase == 0)      { tr[0] = (unsigned)bf; tr[2] = above; }
      else if (phase == 1) { tr[1] = (unsigned)bf; tr[2] = tr[2] + above; }
      else {
        unsigned T = (tr[0] << 20) | (tr[1] << 9) | (unsigned)bf;
        tr[3] = T; tr[4] = target - above;
      }
    }
  } else if (t == 0) {
    if (phase == 0)      { tr[0] = 0xFFFFFFFFu; tr[2] = 0u; }
    else if (phase == 1) { tr[1] = 0xFFFFFFFFu; }
    else                 { tr[3] = 0u; tr[4] = 0u; }
  }
  if (phase == 2 && t == 0) { tr[5] = 0u; tr[6] = 0u; }
}

// ==================== select + decode ====================
__global__ __launch_bounds__(256) void select_k(const float* __restrict__ score,
                                                const float* __restrict__ deltas,
                                                unsigned* __restrict__ thr,
                                                float* __restrict__ cbox, float* __restrict__ csc,
                                                float* __restrict__ ccls, float* __restrict__ cgid,
                                                Geo g)
{
  const int grp = blockIdx.y;
  const int l = grp >> 2, n = grp & 3;
  const int W = g.Wa[l];
  const int HW = g.Ha[l] * W;
  const int M = HW * 80;
  const float stride_ = (float)(8 << l);
  const float* s = score + ((size_t)g.hwOff[l] * 4 + (size_t)n * HW) * 80;
  const float* dBase = deltas + ((size_t)g.hwOff[l] * 4 + (size_t)n * HW) * 4;
  unsigned* tr = thr + grp * 8;
  const unsigned T = tr[3], need = tr[4];
  for (int idx = blockIdx.x * 256 + threadIdx.x; idx < M; idx += gridDim.x * 256) {
    float v = s[idx];
    if (!(v > 0.f)) continue;
    unsigned b = __float_as_uint(v);
    int slot = -1;
    if (b > T) slot = (int)atomicAdd(&tr[5], 1u);
    else if (b == T) {
      unsigned e = atomicAdd(&tr[6], 1u);
      if (e < need) slot = (int)(1000u - need + e);
    }
    if (slot < 0) continue;
    int p = idx / 80, c = idx - p * 80;
    int y = p / W, x = p - y * W;
    const float* d = dBase + (size_t)p * 4;
    float sz  = 8.f * stride_;
    float acx = ((float)x + 0.5f) * stride_;
    float acy = ((float)y + 0.5f) * stride_;
    float dx = d[0] / 10.f, dy = d[1] / 10.f;
    float dw = fminf(d[2] / 5.f, SCALE_CLAMP);
    float dh = fminf(d[3] / 5.f, SCALE_CLAMP);
    float pcx = dx * sz + acx;
    float pcy = dy * sz + acy;
    float pw = expf(dw) * sz;
    float ph = expf(dh) * sz;
    float x1 = pcx - 0.5f * pw, y1_ = pcy - 0.5f * ph;
    float x2 = pcx + 0.5f * pw, y2_ = pcy + 0.5f * ph;
    x1  = fminf(fmaxf(x1, 0.f),  IMG_SIZE);
    y1_ = fminf(fmaxf(y1_, 0.f), IMG_SIZE);
    x2  = fminf(fmaxf(x2, 0.f),  IMG_SIZE);
    y2_ = fminf(fmaxf(y2_, 0.f), IMG_SIZE);
    int cslot = n * 5000 + l * 1000 + slot;
    ((float4*)cbox)[cslot] = make_float4(x1, y1_, x2, y2_);
    csc[cslot]  = sqrtf(v);
    ccls[cslot] = (float)c;
    cgid[cslot] = (float)(((unsigned)l << 20) | (unsigned)idx);
  }
}

// ==================== class-aware greedy NMS ====================
__global__ __launch_bounds__(256) void nms_k(const float* __restrict__ cbox,
                                             const float* __restrict__ csc,
                                             const float* __restrict__ ccls,
                                             const float* __restrict__ cgid,
                                             float* __restrict__ outp)
{
  const int n = blockIdx.x, t = threadIdx.x;
  float sc[20], cl[20], gid[20], bx[20][4];
#pragma unroll
  for (int j = 0; j < 20; ++j) {
    int gidx = j * 256 + t;
    if (gidx < 5000) {
      sc[j] = csc[n * 5000 + gidx];
      float4 b = ((const float4*)cbox)[n * 5000 + gidx];
      bx[j][0] = b.x; bx[j][1] = b.y; bx[j][2] = b.z; bx[j][3] = b.w;
      cl[j]  = ccls[n * 5000 + gidx];
      gid[j] = cgid[n * 5000 + gidx];
    } else { sc[j] = -2.f; bx[j][0] = bx[j][1] = bx[j][2] = bx[j][3] = 0.f; cl[j] = 0.f; gid[j] = 1e9f; }
  }
  __shared__ float rv[4]; __shared__ int rg[4]; __shared__ float rgid[4];
  __shared__ float sbox[4]; __shared__ float scls; __shared__ float sval; __shared__ int sgi;

  for (int it = 0; it < 100; ++it) {
    float bv = -3.f; int bg = 0; float bgid = 2e9f;
#pragma unroll
    for (int j = 0; j < 20; ++j) {
      bool better = (sc[j] > bv) || (sc[j] == bv && gid[j] < bgid);
      if (better) { bv = sc[j]; bg = j * 256 + t; bgid = gid[j]; }
    }
    for (int off = 32; off; off >>= 1) {
      float ov = __shfl_xor(bv, off);
      int   og = __shfl_xor(bg, off);
      float oi = __shfl_xor(bgid, off);
      bool better = (ov > bv) || (ov == bv && oi < bgid);
      if (better) { bv = ov; bg = og; bgid = oi; }
    }
    int wid = t >> 6;
    if ((t & 63) == 0) { rv[wid] = bv; rg[wid] = bg; rgid[wid] = bgid; }
    __syncthreads();
    if (t == 0) {
      float fv = rv[0]; int fg = rg[0]; float fi = rgid[0];
      for (int w = 1; w < 4; ++w) {
        bool better = (rv[w] > fv) || (rv[w] == fv && rgid[w] < fi);
        if (better) { fv = rv[w]; fg = rg[w]; fi = rgid[w]; }
      }
      sval = fv; sgi = fg;
    }
    __syncthreads();
    float best_v = sval; int best_g = sgi;
    if (t == (best_g & 255)) {
      int j = best_g >> 8;
      sbox[0] = bx[j][0]; sbox[1] = bx[j][1]; sbox[2] = bx[j][2]; sbox[3] = bx[j][3];
      scls = cl[j];
    }
    __syncthreads();
    bool valid = best_v > 0.f;
    if (t == 0) {
      int base = n * 100 + it;
      outp[base * 4 + 0] = valid ? sbox[0] : 0.f;
      outp[base * 4 + 1] = valid ? sbox[1] : 0.f;
      outp[base * 4 + 2] = valid ? sbox[2] : 0.f;
      outp[base * 4 + 3] = valid ? sbox[3] : 0.f;
      outp[1600 + base] = valid ? best_v : 0.f;
      outp[2000 + base] = valid ? scls : -1.f;
    }
    float off_ = scls * (2.f * IMG_SIZE);
    float e0 = sbox[0] + off_, e1 = sbox[1] + off_, e2 = sbox[2] + off_, e3 = sbox[3] + off_;
    float a1 = (e2 - e0) * (e3 - e1);
#pragma unroll
    for (int j = 0; j < 20; ++j) {
      float o_ = cl[j] * (2.f * IMG_SIZE);
      float f0 = bx[j][0] + o_, f1 = bx[j][1] + o_, f2 = bx[j][2] + o_, f3 = bx[j][3] + o_;
      float xx1 = fmaxf(e0, f0), yy1 = fmaxf(e1, f1);
      float xx2 = fminf(e2, f2), yy2 = fminf(e3, f3);
      float inter = fmaxf(xx2 - xx1, 0.f) * fmaxf(yy2 - yy1, 0.f);
      float a2 = (f2 - f0) * (f3 - f1);
      float iou = inter / (a1 + a2 - inter + 1e-9f);
      if (iou > 0.6f) sc[j] = -1.f;
      if ((j * 256 + t) == best_g) sc[j] = -1.f;
    }
    __syncthreads();
  }
}

// ==================== host ====================
extern "C" void kernel_launch(void* const* d_in, const int* in_sizes, int n_in,
                              void* d_out, int out_size, void* d_ws, size_t ws_size,
                              hipStream_t stream)
{
  (void)in_sizes; (void)n_in; (void)out_size; (void)ws_size;
  const float* p3 = (const float*)d_in[0];
  const float* p4 = (const float*)d_in[1];
  const float* p5 = (const float*)d_in[2];
  const float* p6 = (const float*)d_in[3];
  const float* p7 = (const float*)d_in[4];
  const float* cls_tw  = (const float*)d_in[5];
  const float* cls_tb  = (const float*)d_in[6];
  const float* bbox_tw = (const float*)d_in[7];
  const float* bbox_tb = (const float*)d_in[8];
  const float* wcls    = (const float*)d_in[9];
  const float* bcls    = (const float*)d_in[10];
  const float* wbox    = (const float*)d_in[11];
  const float* bbox_b  = (const float*)d_in[12];
  const float* wctr    = (const float*)d_in[13];
  const float* bctr    = (const float*)d_in[14];
  const float* scales  = (const float*)d_in[15];
  float* out = (float*)d_out;

  // geometry (conv tiles now 4 rows x 16 cols)
  Geo G;
  const int Hs[5] = {100, 50, 25, 13, 7};
  {
    int tpre = 0, ppre = 0, bpre = 0, phw = 0, hw = 0;
    for (int l = 0; l < 5; ++l) {
      int H = Hs[l], W = Hs[l];
      G.Ha[l] = H; G.Wa[l] = W; G.PWa[l] = W + 2; G.PHWa[l] = (H + 2) * (W + 2);
      G.TXa[l] = (W + 15) / 16;
      int TY = (H + 3) / 4;
      G.tp[l] = tpre;  tpre += G.TXa[l] * TY;
      G.pb[l] = ppre;  ppre += (H * W + 63) / 64;
      G.bb[l] = bpre;  bpre += (H * W + 255) / 256;
      G.phwOff[l] = phw; phw += G.PHWa[l];
      G.hwOff[l]  = hw;  hw  += H * W;
    }
    G.tp[5] = tpre; G.pb[5] = ppre; G.bb[5] = bpre;
  }
  const int nTiles = G.tp[5];   // 247
  const int nPrep  = G.pb[5];   // 211
  const int nBoxB  = G.bb[5];   // 55
  const int sumHW = 13343;
  const size_t scoreBytes  = (size_t)sumHW * 4 * 80 * 4;
  const size_t deltasBytes = (size_t)sumHW * 4 * 4 * 4;

  char* ws = (char*)d_ws;
  size_t off = 0;
  auto alloc = [&](size_t bytes) -> void* {
    off = (off + 255) & ~(size_t)255;
    void* p = ws + off; off += bytes; return p;
  };
  const size_t bufBytes = 3ull * PLANE * 2;   // one split-plane act buffer = 86.9 MB

  short* wt     = (short*)alloc((size_t)8 * 3 * 589824 * 2);
  float* cbox   = (float*)alloc(4ull * 5000 * 4 * 4);
  float* csc    = (float*)alloc(4ull * 5000 * 4);
  float* ccls   = (float*)alloc(4ull * 5000 * 4);
  float* cgid   = (float*)alloc(4ull * 5000 * 4);
  unsigned* hist = (unsigned*)alloc(20ull * 2048 * 4);
  unsigned* thr  = (unsigned*)alloc(20ull * 8 * 4);
  short* A = (short*)alloc(bufBytes);
  short* B = (short*)alloc(bufBytes);
  float* score  = (float*)alloc(scoreBytes);
  float* deltas = (float*)alloc(deltasBytes);

  hipMemsetAsync(cbox, 0, 4ull * 5000 * 4 * 4, stream);
  hipMemsetAsync(csc,  0, 4ull * 5000 * 4, stream);
  hipMemsetAsync(ccls, 0, 4ull * 5000 * 4, stream);
  hipMemsetAsync(cgid, 0, 4ull * 5000 * 4, stream);
  hipMemsetAsync(thr,  0, 20ull * 8 * 4, stream);
  hipMemsetAsync(A, 0, bufBytes, stream);
  hipMemsetAsync(B, 0, bufBytes, stream);

  wtrans_k<<<1024, 256, 0, stream>>>(cls_tw, bbox_tw, wt);

  const size_t LSTRIDE = 3ull * 589824;  // shorts per conv layer (3 planes)
  dim3 cg(nTiles, 2, 4);  // 1976 blocks/dispatch

  // cls tower: prep->A, A->B->A->B->A, head(A)
  prep_all_k<<<dim3(nPrep, 4), 256, 0, stream>>>(p3, p4, p5, p6, p7, A, G);
  conv_all_k<<<cg, 256, 0, stream>>>(A, A, wt + 0 * LSTRIDE, wt + 0 * LSTRIDE,
                                     cls_tb + 0 * 256, cls_tb + 0 * 256, B, B, G);
  conv_all_k<<<cg, 256, 0, stream>>>(B, B, wt + 1 * LSTRIDE, wt + 1 * LSTRIDE,
                                     cls_tb + 1 * 256, cls_tb + 1 * 256, A, A, G);
  conv_all_k<<<cg, 256, 0, stream>>>(A, A, wt + 2 * LSTRIDE, wt + 2 * LSTRIDE,
                                     cls_tb + 2 * 256, cls_tb + 2 * 256, B, B, G);
  conv_all_k<<<cg, 256, 0, stream>>>(B, B, wt + 3 * LSTRIDE, wt + 3 * LSTRIDE,
                                     cls_tb + 3 * 256, cls_tb + 3 * 256, A, A, G);
  cls_head_k<<<dim3(nPrep, 4), 256, 0, stream>>>(A, wcls, bcls, score, G);
  // bbox tower: re-prep->B, B->A->B->A->B, head(B)
  prep_all_k<<<dim3(nPrep, 4), 256, 0, stream>>>(p3, p4, p5, p6, p7, B, G);
  conv_all_k<<<cg, 256, 0, stream>>>(B, B, wt + 4 * LSTRIDE, wt + 4 * LSTRIDE,
                                     bbox_tb + 0 * 256, bbox_tb + 0 * 256, A, A, G);
  conv_all_k<<<cg, 256, 0, stream>>>(A, A, wt + 5 * LSTRIDE, wt + 5 * LSTRIDE,
                                     bbox_tb + 1 * 256, bbox_tb + 1 * 256, B, B, G);
  conv_all_k<<<cg, 256, 0, stream>>>(B, B, wt + 6 * LSTRIDE, wt + 6 * LSTRIDE,
                                     bbox_tb + 2 * 256, bbox_tb + 2 * 256, A, A, G);
  conv_all_k<<<cg, 256, 0, stream>>>(A, A, wt + 7 * LSTRIDE, wt + 7 * LSTRIDE,
                                     bbox_tb + 3 * 256, bbox_tb + 3 * 256, B, B, G);
  box_head_k<<<dim3(nBoxB, 4), 256, 0, stream>>>(B, wbox, bbox_b, wctr, bctr, scales,
                                                 score, deltas, G);

  // exact top-1000 per (level, image)
  const int hb = 196;
  for (int phase = 0; phase < 3; ++phase) {
    hipMemsetAsync(hist, 0, 20ull * 2048 * 4, stream);
    hist_k<<<dim3(hb, 20), 256, 0, stream>>>(score, thr, hist, phase, G);
    scan_k<<<20, 256, 0, stream>>>(hist, thr, phase);
  }
  select_k<<<dim3(hb, 20), 256, 0, stream>>>(score, deltas, thr, cbox, csc, ccls, cgid, G);

  nms_k<<<4, 256, 0, stream>>>(cbox, csc, ccls, cgid, out);
}

// Round 10
// 2222.639 us; speedup vs baseline: 1.9209x; 1.5409x over previous
//
#include <hip/hip_runtime.h>
#include <math.h>

typedef short s8v __attribute__((ext_vector_type(8)));
typedef short s4v __attribute__((ext_vector_type(4)));
typedef float f4v __attribute__((ext_vector_type(4)));
typedef _Float16 h8v __attribute__((ext_vector_type(8)));

__device__ __forceinline__ float sigf(float x) { return 1.f / (1.f + expf(-x)); }
__device__ __forceinline__ float f16f(short v) {
  return (float)__builtin_bit_cast(_Float16, v);
}

#define SCALE_CLAMP 4.135166556742356f
#define IMG_SIZE 800.f
#define PLANE 14482432ull   // shorts per activation plane: sumPHW(14143)*4*256
#define W_SCALE 1024.f      // weight pre-scale (keeps w_l in fp16 normal range)
#define A_SCALE 64.f        // activation pre-scale
#define ACC_RESCALE 1.52587890625e-5f   // 2^-16 = 1/(W_SCALE*A_SCALE)

// fp16 2-way split (round-to-nearest): x ~= h + l, residual <= 2^-24 |x|
__device__ __forceinline__ void split2(float x, short& h, short& l) {
  _Float16 hf = (_Float16)x;
  _Float16 lf = (_Float16)(x - (float)hf);
  h = __builtin_bit_cast(short, hf);
  l = __builtin_bit_cast(short, lf);
}

struct Geo {
  int tp[6];                 // conv tile prefix per level (4x16 tiles)
  int TXa[5];
  int Ha[5], Wa[5], PWa[5], PHWa[5];
  int phwOff[5];             // PHW prefix
  int hwOff[5];              // HW prefix
  int pb[6];                 // ceil(HW/64) prefix  (prep + cls head)
  int bb[6];                 // ceil(HW/256) prefix (box head)
};

// ==================== weight split+transpose (fp16 h/l, x1024) ====================
// out layout (fp16 shorts): [layer8][plane2][ (tap*8+cc)*4+q ][ko 256][e 8]
__global__ __launch_bounds__(256) void wtrans_k(const float* __restrict__ cls_tw,
                                                const float* __restrict__ bbox_tw,
                                                short* __restrict__ wt)
{
  const int total = 589824;
  for (int u = blockIdx.x * 256 + threadIdx.x; u < total; u += gridDim.x * 256) {
    int layer = u / 73728;
    int r = u - layer * 73728;
    int tap = r / 8192;  r -= tap * 8192;
    int cc  = r / 1024;  r -= cc * 1024;
    int qq  = r / 256;   int ko = r - qq * 256;
    int cibase = cc * 32 + qq * 8;
    const float* src = (layer < 4) ? (cls_tw + (size_t)layer * 589824)
                                   : (bbox_tw + (size_t)(layer - 4) * 589824);
    s8v hv, lv;
#pragma unroll
    for (int e = 0; e < 8; ++e) {
      float x = src[(size_t)ko * 2304 + (size_t)(cibase + e) * 9 + tap] * W_SCALE;
      short h, l; split2(x, h, l);
      hv[e] = h; lv[e] = l;
    }
    size_t dbase = (size_t)layer * 1179648 + (((size_t)tap * 8 + cc) * 4 + qq) * 2048 + (size_t)ko * 8;
    *(s8v*)(wt + dbase) = hv;
    *(s8v*)(wt + dbase + 589824) = lv;
  }
}

// ==================== NCHW fp32 -> padded split-plane fp16x2 (x64) ====================
__global__ __launch_bounds__(256) void prep_all_k(const float* __restrict__ p3, const float* __restrict__ p4,
                                                  const float* __restrict__ p5, const float* __restrict__ p6,
                                                  const float* __restrict__ p7,
                                                  short* __restrict__ out, Geo g)
{
  __shared__ float tl[64][260];
  int bx = blockIdx.x, t = threadIdx.x, n = blockIdx.y;
  int l = 0; while (l < 4 && bx >= g.pb[l + 1]) ++l;
  const float* in = (l == 0) ? p3 : (l == 1) ? p4 : (l == 2) ? p5 : (l == 3) ? p6 : p7;
  int H = g.Ha[l], W = g.Wa[l], PW = g.PWa[l], PHW = g.PHWa[l], HW = H * W;
  int P0 = (bx - g.pb[l]) * 64;
  const float* inN = in + (size_t)n * HW * 256;
  int sub = t >> 6, pl = t & 63;
  int pos = P0 + pl;
  for (int i = 0; i < 64; ++i) {
    int ci = i * 4 + sub;
    tl[pl][ci] = (pos < HW) ? inN[(size_t)ci * HW + pos] : 0.f;
  }
  __syncthreads();
  int pl2 = t >> 2, cq = (t & 3) * 64;
  int pos2 = P0 + pl2;
  if (pos2 < HW) {
    int y = pos2 / W, x = pos2 - y * W;
    size_t oo = ((size_t)g.phwOff[l] * 4 + (size_t)n * PHW + (size_t)(y + 1) * PW + (x + 1)) * 256 + cq;
#pragma unroll
    for (int grp = 0; grp < 8; ++grp) {
      s8v hv, lv;
#pragma unroll
      for (int e = 0; e < 8; ++e) {
        short h, lo; split2(tl[pl2][cq + grp * 8 + e] * A_SCALE, h, lo);
        hv[e] = h; lv[e] = lo;
      }
      *(s8v*)(out + oo + grp * 8) = hv;
      *(s8v*)(out + PLANE + oo + grp * 8) = lv;
    }
  }
}

// ==================== MFMA conv 3x3 + bias + relu (fp16 16x16x32, 3 products) ====================
// Tile 4x16 pos x 128 ko; 4 waves (wcol x wko), per wave acc[2][4] (32 f32).
// fp16 split2: products hh + hl + lh (ll ~ 2^-24 dropped) -> 24 MFMA/tap (was 48).
// LDS: 2 planes x 448 slots x 16B x 2buf = 28.7KB. QS=112 (112*16B = 0 mod 32 banks:
// sigma-rotation (pos+2q)%112 gives q bank bases {0,8,16,24}; wrap is bank-neutral).
// Weights global(L2)->reg, ni-half pipelined. ~110 VGPR -> 4 waves/SIMD.
#define QS    112
#define QVALID 108
#define PSTR  3584   // shorts per plane (448*8)
#define BSTR  7168   // shorts per buffer (2 planes)
__global__ __launch_bounds__(256, 4) void conv_all_k(const short* __restrict__ in0,
                                                     const short* __restrict__ in1,
                                                     const short* __restrict__ wt0,
                                                     const short* __restrict__ wt1,
                                                     const float* __restrict__ bias0,
                                                     const float* __restrict__ bias1,
                                                     short* __restrict__ out0,
                                                     short* __restrict__ out1, Geo g)
{
  __shared__ short act_s[2 * BSTR];  // 28672 B

  const int t = threadIdx.x;
  const int lane = t & 63, wave = t >> 6;
  const int wcol = wave & 1, wko = wave >> 1;
  const int tower = blockIdx.z >> 2;
  const int n = blockIdx.z & 3;
  const short* in   = tower ? in1 : in0;
  const short* wtL  = tower ? wt1 : wt0;
  const float* bias = tower ? bias1 : bias0;
  short* out        = tower ? out1 : out0;
  const int ko0 = blockIdx.y * 128;
  int bx = blockIdx.x;
  int l = 0; while (l < 4 && bx >= g.tp[l + 1]) ++l;
  const int H = g.Ha[l], W = g.Wa[l], PW = g.PWa[l], PHW = g.PHWa[l];
  const int lt = bx - g.tp[l];
  const int TX = g.TXa[l];
  const int ty = lt / TX, tx = lt - ty * TX;
  const int R0 = ty * 4, C0 = tx * 16;
  const size_t bi = ((size_t)g.phwOff[l] * 4 + (size_t)n * PHW) * 256;
  const short* inN = in + bi;
  short* outN = out + bi;

  const int r = lane & 15, q = lane >> 4;
  const int cb = wcol * 8;
  const short* wlane = wtL + (size_t)q * 2048 + (size_t)(ko0 + wko * 64 + r) * 8;

  // staging GLOBAL source offsets (sigma-inverse on source; DMA dest stays linear)
  int soff[2];
#pragma unroll
  for (int k = 0; k < 2; ++k) {
    int j = t + k * 256; if (j > 447) j = 447;
    int qq = j / QS, ppos = j - qq * QS;
    int lpos = ppos - 2 * qq; if (lpos < 0) lpos += QS;
    if (lpos >= QVALID) lpos = QVALID - 1;   // dead slot (never read)
    int row = lpos / 18, col = lpos - row * 18;
    int prow = R0 + row; if (prow > H + 1) prow = H + 1;
    int pcol = C0 + col; if (pcol > W + 1) pcol = W + 1;
    soff[k] = (prow * PW + pcol) * 256 + qq * 8;
  }

  f4v acc[2][4];
#pragma unroll
  for (int mi = 0; mi < 2; ++mi)
#pragma unroll
    for (int ni = 0; ni < 4; ++ni) { f4v z = {0.f, 0.f, 0.f, 0.f}; acc[mi][ni] = z; }

  auto stage = [&](int cc, int buf) {
#pragma unroll
    for (int k = 0; k < 2; ++k) {
      int j = t + k * 256;
      if (j < 448) {  // wave-uniform: only wave 3 skips k=1
#pragma unroll
        for (int p = 0; p < 2; ++p) {
          const short* src = inN + (size_t)p * PLANE + (size_t)(soff[k] + cc * 32);
          short* dst = &act_s[(size_t)buf * BSTR + (size_t)p * PSTR + (size_t)j * 8];
#if __has_builtin(__builtin_amdgcn_global_load_lds)
          __builtin_amdgcn_global_load_lds((const __attribute__((address_space(1))) void*)src,
                                           (__attribute__((address_space(3))) void*)dst, 16, 0, 0);
#else
          *(s8v*)dst = *(const s8v*)src;
#endif
        }
      }
    }
  };

  // weights: half = ni pair {0,1} or {2,3}; 4 x 16B loads from L2
  auto loadW = [&](s8v (&w)[2][2], int cc2, int tap2, int half) {
    const short* base = wlane + (size_t)(tap2 * 8 + cc2) * 8192 + half * 256;
#pragma unroll
    for (int p = 0; p < 2; ++p)
#pragma unroll
      for (int k = 0; k < 2; ++k)
        w[p][k] = *(const s8v*)(base + (size_t)p * 589824 + k * 128);
  };

  auto loadA = [&](s8v (&af)[2][2], int dy, int dx, int buf) {
    const int sbase = buf * BSTR;
#pragma unroll
    for (int mi = 0; mi < 2; ++mi) {
      int lp = (2 * mi + (r >> 3) + dy) * 18 + (cb + (r & 7) + dx) + 2 * q;
      if (lp >= QS) lp -= QS;    // wrap is bank-neutral at QS=112
      int sl = q * QS + lp;
      af[0][mi] = *(const s8v*)&act_s[sbase + sl * 8];
      af[1][mi] = *(const s8v*)&act_s[sbase + PSTR + sl * 8];
    }
  };

  // 3 products: hh, hl, lh
  auto runHalf = [&](const s8v (&w)[2][2], const s8v (&af)[2][2], int half) {
    const int PA[3] = {0, 0, 1};
    const int PB[3] = {0, 1, 0};
    __builtin_amdgcn_s_setprio(1);
#pragma unroll
    for (int pp = 0; pp < 3; ++pp)
#pragma unroll
      for (int mi = 0; mi < 2; ++mi)
#pragma unroll
        for (int k = 0; k < 2; ++k)
          acc[mi][half * 2 + k] = __builtin_amdgcn_mfma_f32_16x16x32_f16(
              __builtin_bit_cast(h8v, af[PA[pp]][mi]),
              __builtin_bit_cast(h8v, w[PB[pp]][k]),
              acc[mi][half * 2 + k], 0, 0, 0);
    __builtin_amdgcn_s_setprio(0);
  };

  s8v wH0[2][2], wH1[2][2], afr[2][2];
  stage(0, 0);
  loadW(wH0, 0, 0, 0);
  __syncthreads();            // vmcnt(0) drained before barrier

  int cur = 0;
  for (int cc = 0; cc < 8; ++cc) {
    if (cc < 7) stage(cc + 1, cur ^ 1);   // DMA hides under this cc's 216 MFMAs
#pragma unroll
    for (int tap = 0; tap < 9; ++tap) {
      const int dy = tap / 3, dx = tap - dy * 3;
      loadW(wH1, cc, tap, 1);             // issue half1 (current tap)
      loadA(afr, dy, dx, cur);
      runHalf(wH0, afr, 0);               // half0 (prefetched last phase)
      int ntap = tap + 1, ncc = cc;
      if (ntap == 9) { ntap = 0; ++ncc; }
      if (ncc < 8) loadW(wH0, ncc, ntap, 0);  // issue next tap's half0
      runHalf(wH1, afr, 1);
    }
    __syncthreads();          // vmcnt drain (DMA landed) + all waves done with act_s[cur]
    cur ^= 1;
  }

  // epilogue: rescale + bias + relu + split2(x64), store 2 fp16 planes (masked)
#pragma unroll
  for (int mi = 0; mi < 2; ++mi) {
#pragma unroll
    for (int ni = 0; ni < 4; ++ni) {
      int ko = ko0 + wko * 64 + ni * 16 + r;
      float bv = bias[ko];
#pragma unroll
      for (int reg = 0; reg < 4; ++reg) {
        int rm = q * 4 + reg;
        int orow = R0 + 2 * mi + (rm >> 3);
        int ocol = C0 + cb + (rm & 7);
        if (orow < H && ocol < W) {
          float real = acc[mi][ni][reg] * ACC_RESCALE + bv;
          float vv = fmaxf(real, 0.f) * A_SCALE;
          short h, lo; split2(vv, h, lo);
          size_t oo = ((size_t)(orow + 1) * PW + (ocol + 1)) * 256 + ko;
          outN[oo] = h; outN[PLANE + oo] = lo;
        }
      }
    }
  }
}

// ==================== cls head (all levels): 1x1x80 + sigmoid ====================
__global__ __launch_bounds__(256) void cls_head_k(const short* __restrict__ act,
                                                  const float* __restrict__ wcls,
                                                  const float* __restrict__ bcls,
                                                  float* __restrict__ score, Geo g)
{
  __shared__ int   p2s[64];
  __shared__ float as_[64][69];
  __shared__ float ws_[64][84];
  const int t = threadIdx.x;
  const int n = blockIdx.y;
  int bx = blockIdx.x;
  int l = 0; while (l < 4 && bx >= g.pb[l + 1]) ++l;
  const int H = g.Ha[l], W = g.Wa[l], PW = g.PWa[l], PHW = g.PHWa[l], HW = H * W;
  const int P0 = (bx - g.pb[l]) * 64;
  if (t < 64) {
    int p = P0 + t; if (p >= HW) p = HW - 1;
    int y = p / W, x = p - y * W;
    p2s[t] = (y + 1) * PW + x + 1;
  }
  __syncthreads();
  float accv[4][5];
#pragma unroll
  for (int i = 0; i < 4; ++i)
#pragma unroll
    for (int j = 0; j < 5; ++j) accv[i][j] = 0.f;

  const short* actN = act + ((size_t)g.phwOff[l] * 4 + (size_t)n * PHW) * 256;
  const int pg = t >> 4, cg = t & 15;
  const float inv = 1.f / A_SCALE;

  for (int c0 = 0; c0 < 256; c0 += 64) {
    for (int i = t; i < 1024; i += 256) {
      int pos = i >> 4, c4 = i & 15;
      size_t o = (size_t)p2s[pos] * 256 + c0 + c4 * 4;
      s4v hv = *(const s4v*)(actN + o);
      s4v lv = *(const s4v*)(actN + PLANE + o);
      float* dst = &as_[pos][c4 * 4];
#pragma unroll
      for (int e = 0; e < 4; ++e) dst[e] = (f16f(hv[e]) + f16f(lv[e])) * inv;
    }
    for (int i = t; i < 1280; i += 256) {
      int c = i >> 4, c4 = i & 15;
      float4 v = *(const float4*)(wcls + (size_t)c * 256 + c0 + c4 * 4);
      ws_[c4 * 4 + 0][c] = v.x; ws_[c4 * 4 + 1][c] = v.y;
      ws_[c4 * 4 + 2][c] = v.z; ws_[c4 * 4 + 3][c] = v.w;
    }
    __syncthreads();
#pragma unroll 8
    for (int ci = 0; ci < 64; ++ci) {
#pragma unroll
      for (int i = 0; i < 4; ++i) {
        float a = as_[pg * 4 + i][ci];
#pragma unroll
        for (int j = 0; j < 5; ++j)
          accv[i][j] = fmaf(a, ws_[ci][cg * 5 + j], accv[i][j]);
      }
    }
    __syncthreads();
  }
  float* sB = score + ((size_t)g.hwOff[l] * 4 + (size_t)n * HW) * 80;
#pragma unroll
  for (int i = 0; i < 4; ++i) {
    int p = P0 + pg * 4 + i;
    if (p >= HW) continue;
#pragma unroll
    for (int j = 0; j < 5; ++j) {
      int c = cg * 5 + j;
      sB[(size_t)p * 80 + c] = sigf(accv[i][j] + bcls[c]);
    }
  }
}

// ==================== box head (all levels) ====================
__global__ __launch_bounds__(256) void box_head_k(const short* __restrict__ act,
                                                  const float* __restrict__ wbox,
                                                  const float* __restrict__ bb,
                                                  const float* __restrict__ wctr,
                                                  const float* __restrict__ bc,
                                                  const float* __restrict__ scales,
                                                  float* __restrict__ score,
                                                  float* __restrict__ deltas, Geo g)
{
  int n = blockIdx.y;
  int bx = blockIdx.x;
  int l = 0; while (l < 4 && bx >= g.bb[l + 1]) ++l;
  const int H = g.Ha[l], W = g.Wa[l], PW = g.PWa[l], PHW = g.PHWa[l], HW = H * W;
  int p = (bx - g.bb[l]) * 256 + threadIdx.x;
  if (p >= HW) return;
  int y = p / W, x = p - y * W;
  const short* a = act + ((size_t)g.phwOff[l] * 4 + (size_t)n * PHW + (size_t)(y + 1) * PW + x + 1) * 256;
  const float inv = 1.f / A_SCALE;
  float d0 = 0, d1 = 0, d2 = 0, d3 = 0, ct = 0;
  for (int gI = 0; gI < 32; ++gI) {
    s8v hv = *(const s8v*)(a + gI * 8);
    s8v lv = *(const s8v*)(a + PLANE + gI * 8);
#pragma unroll
    for (int e = 0; e < 8; ++e) {
      float av = (f16f(hv[e]) + f16f(lv[e])) * inv;
      int c = gI * 8 + e;
      d0 = fmaf(av, wbox[c], d0);
      d1 = fmaf(av, wbox[256 + c], d1);
      d2 = fmaf(av, wbox[512 + c], d2);
      d3 = fmaf(av, wbox[768 + c], d3);
      ct = fmaf(av, wctr[c], ct);
    }
  }
  float sl = scales[l];
  float* dd = deltas + ((size_t)g.hwOff[l] * 4 + (size_t)n * HW + p) * 4;
  dd[0] = sl * (d0 + bb[0]); dd[1] = sl * (d1 + bb[1]);
  dd[2] = sl * (d2 + bb[2]); dd[3] = sl * (d3 + bb[3]);
  float sct = sigf(ct + bc[0]);
  float* sp = score + ((size_t)g.hwOff[l] * 4 + (size_t)n * HW + p) * 80;
#pragma unroll
  for (int i = 0; i < 20; ++i) {
    float4 v = ((float4*)sp)[i];
    v.x *= sct; v.y *= sct; v.z *= sct; v.w *= sct;
    v.x = (v.x > 0.05f) ? v.x : 0.f;
    v.y = (v.y > 0.05f) ? v.y : 0.f;
    v.z = (v.z > 0.05f) ? v.z : 0.f;
    v.w = (v.w > 0.05f) ? v.w : 0.f;
    ((float4*)sp)[i] = v;
  }
}

// ==================== exact top-1000: 3-pass bit histogram, 20 (level,image) groups ====================
__global__ __launch_bounds__(256) void hist_k(const float* __restrict__ score,
                                              const unsigned* __restrict__ thr,
                                              unsigned* __restrict__ hist, int phase, Geo g)
{
  const int grp = blockIdx.y;
  const int l = grp >> 2, n = grp & 3;
  const int HW = g.Ha[l] * g.Wa[l];
  const int M = HW * 80;
  const float* s = score + ((size_t)g.hwOff[l] * 4 + (size_t)n * HW) * 80;
  unsigned* h = hist + grp * 2048;
  const unsigned* tr = thr + grp * 8;
  __shared__ unsigned lh[2048];
  for (int i = threadIdx.x; i < 2048; i += 256) lh[i] = 0u;
  __syncthreads();
  unsigned B1 = 0, pref = 0;
  if (phase == 1) B1 = tr[0];
  if (phase == 2) pref = (tr[0] << 11) | tr[1];
  for (int idx = blockIdx.x * 256 + threadIdx.x; idx < M; idx += gridDim.x * 256) {
    float v = s[idx];
    if (v > 0.f) {
      unsigned b = __float_as_uint(v);
      if (phase == 0) atomicAdd(&lh[b >> 20], 1u);
      else if (phase == 1) { if ((b >> 20) == B1) atomicAdd(&lh[(b >> 9) & 0x7FFu], 1u); }
      else { if ((b >> 9) == pref) atomicAdd(&lh[b & 0x1FFu], 1u); }
    }
  }
  __syncthreads();
  for (int i = threadIdx.x; i < 2048; i += 256) { unsigned v = lh[i]; if (v) atomicAdd(&h[i], v); }
}

__global__ __launch_bounds__(256) void scan_k(unsigned* __restrict__ hist,
                                              unsigned* __restrict__ thr, int phase)
{
  const int grp = blockIdx.x, t = threadIdx.x;
  unsigned* h  = hist + grp * 2048;
  unsigned* tr = thr + grp * 8;
  const int nb = (phase == 2) ? 512 : 2048;
  const int PB = nb / 256;
  unsigned target = 1000u;
  bool dead = false;
  if (phase >= 1) {
    target = 1000u - tr[2];
    if (tr[0] == 0xFFFFFFFFu) dead = true;
    if (phase == 2 && tr[1] == 0xFFFFFFFFu) dead = true;
  }
  __shared__ unsigned ps[256];
  __shared__ unsigned s_tot;
  const int hi = nb - t * PB;
  unsigned lsum = 0;
  for (int k = 0; k < PB; ++k) lsum += h[hi - 1 - k];
  ps[t] = lsum;
  __syncthreads();
  if (t == 0) {
    unsigned cum = 0;
    for (int i = 0; i < 256; ++i) { unsigned tmp = ps[i]; ps[i] = cum; cum += tmp; }
    s_tot = cum;
  }
  __syncthreads();
  unsigned exc = ps[t], tot = s_tot;
  if (!dead && tot >= target) {
    if (exc < target && exc + lsum >= target) {
      unsigned cum = exc; int bf = 0; unsigned above = 0;
      for (int k = 0; k < PB; ++k) {
        int bidx = hi - 1 - k;
        unsigned c = h[bidx];
        if (cum < target && cum + c >= target) { bf = bidx; above = cum; }
        cum += c;
      }
      if (phase == 0)      { tr[0] = (unsigned)bf; tr[2] = above; }
      else if (phase == 1) { tr[1] = (unsigned)bf; tr[2] = tr[2] + above; }
      else {
        unsigned T = (tr[0] << 20) | (tr[1] << 9) | (unsigned)bf;
        tr[3] = T; tr[4] = target - above;
      }
    }
  } else if (t == 0) {
    if (phase == 0)      { tr[0] = 0xFFFFFFFFu; tr[2] = 0u; }
    else if (phase == 1) { tr[1] = 0xFFFFFFFFu; }
    else                 { tr[3] = 0u; tr[4] = 0u; }
  }
  if (phase == 2 && t == 0) { tr[5] = 0u; tr[6] = 0u; }
}

// ==================== select + decode ====================
__global__ __launch_bounds__(256) void select_k(const float* __restrict__ score,
                                                const float* __restrict__ deltas,
                                                unsigned* __restrict__ thr,
                                                float* __restrict__ cbox, float* __restrict__ csc,
                                                float* __restrict__ ccls, float* __restrict__ cgid,
                                                Geo g)
{
  const int grp = blockIdx.y;
  const int l = grp >> 2, n = grp & 3;
  const int W = g.Wa[l];
  const int HW = g.Ha[l] * W;
  const int M = HW * 80;
  const float stride_ = (float)(8 << l);
  const float* s = score + ((size_t)g.hwOff[l] * 4 + (size_t)n * HW) * 80;
  const float* dBase = deltas + ((size_t)g.hwOff[l] * 4 + (size_t)n * HW) * 4;
  unsigned* tr = thr + grp * 8;
  const unsigned T = tr[3], need = tr[4];
  for (int idx = blockIdx.x * 256 + threadIdx.x; idx < M; idx += gridDim.x * 256) {
    float v = s[idx];
    if (!(v > 0.f)) continue;
    unsigned b = __float_as_uint(v);
    int slot = -1;
    if (b > T) slot = (int)atomicAdd(&tr[5], 1u);
    else if (b == T) {
      unsigned e = atomicAdd(&tr[6], 1u);
      if (e < need) slot = (int)(1000u - need + e);
    }
    if (slot < 0) continue;
    int p = idx / 80, c = idx - p * 80;
    int y = p / W, x = p - y * W;
    const float* d = dBase + (size_t)p * 4;
    float sz  = 8.f * stride_;
    float acx = ((float)x + 0.5f) * stride_;
    float acy = ((float)y + 0.5f) * stride_;
    float dx = d[0] / 10.f, dy = d[1] / 10.f;
    float dw = fminf(d[2] / 5.f, SCALE_CLAMP);
    float dh = fminf(d[3] / 5.f, SCALE_CLAMP);
    float pcx = dx * sz + acx;
    float pcy = dy * sz + acy;
    float pw = expf(dw) * sz;
    float ph = expf(dh) * sz;
    float x1 = pcx - 0.5f * pw, y1_ = pcy - 0.5f * ph;
    float x2 = pcx + 0.5f * pw, y2_ = pcy + 0.5f * ph;
    x1  = fminf(fmaxf(x1, 0.f),  IMG_SIZE);
    y1_ = fminf(fmaxf(y1_, 0.f), IMG_SIZE);
    x2  = fminf(fmaxf(x2, 0.f),  IMG_SIZE);
    y2_ = fminf(fmaxf(y2_, 0.f), IMG_SIZE);
    int cslot = n * 5000 + l * 1000 + slot;
    ((float4*)cbox)[cslot] = make_float4(x1, y1_, x2, y2_);
    csc[cslot]  = sqrtf(v);
    ccls[cslot] = (float)c;
    cgid[cslot] = (float)(((unsigned)l << 20) | (unsigned)idx);
  }
}

// ==================== class-aware greedy NMS ====================
__global__ __launch_bounds__(256) void nms_k(const float* __restrict__ cbox,
                                             const float* __restrict__ csc,
                                             const float* __restrict__ ccls,
                                             const float* __restrict__ cgid,
                                             float* __restrict__ outp)
{
  const int n = blockIdx.x, t = threadIdx.x;
  float sc[20], cl[20], gid[20], bx[20][4];
#pragma unroll
  for (int j = 0; j < 20; ++j) {
    int gidx = j * 256 + t;
    if (gidx < 5000) {
      sc[j] = csc[n * 5000 + gidx];
      float4 b = ((const float4*)cbox)[n * 5000 + gidx];
      bx[j][0] = b.x; bx[j][1] = b.y; bx[j][2] = b.z; bx[j][3] = b.w;
      cl[j]  = ccls[n * 5000 + gidx];
      gid[j] = cgid[n * 5000 + gidx];
    } else { sc[j] = -2.f; bx[j][0] = bx[j][1] = bx[j][2] = bx[j][3] = 0.f; cl[j] = 0.f; gid[j] = 1e9f; }
  }
  __shared__ float rv[4]; __shared__ int rg[4]; __shared__ float rgid[4];
  __shared__ float sbox[4]; __shared__ float scls; __shared__ float sval; __shared__ int sgi;

  for (int it = 0; it < 100; ++it) {
    float bv = -3.f; int bg = 0; float bgid = 2e9f;
#pragma unroll
    for (int j = 0; j < 20; ++j) {
      bool better = (sc[j] > bv) || (sc[j] == bv && gid[j] < bgid);
      if (better) { bv = sc[j]; bg = j * 256 + t; bgid = gid[j]; }
    }
    for (int off = 32; off; off >>= 1) {
      float ov = __shfl_xor(bv, off);
      int   og = __shfl_xor(bg, off);
      float oi = __shfl_xor(bgid, off);
      bool better = (ov > bv) || (ov == bv && oi < bgid);
      if (better) { bv = ov; bg = og; bgid = oi; }
    }
    int wid = t >> 6;
    if ((t & 63) == 0) { rv[wid] = bv; rg[wid] = bg; rgid[wid] = bgid; }
    __syncthreads();
    if (t == 0) {
      float fv = rv[0]; int fg = rg[0]; float fi = rgid[0];
      for (int w = 1; w < 4; ++w) {
        bool better = (rv[w] > fv) || (rv[w] == fv && rgid[w] < fi);
        if (better) { fv = rv[w]; fg = rg[w]; fi = rgid[w]; }
      }
      sval = fv; sgi = fg;
    }
    __syncthreads();
    float best_v = sval; int best_g = sgi;
    if (t == (best_g & 255)) {
      int j = best_g >> 8;
      sbox[0] = bx[j][0]; sbox[1] = bx[j][1]; sbox[2] = bx[j][2]; sbox[3] = bx[j][3];
      scls = cl[j];
    }
    __syncthreads();
    bool valid = best_v > 0.f;
    if (t == 0) {
      int base = n * 100 + it;
      outp[base * 4 + 0] = valid ? sbox[0] : 0.f;
      outp[base * 4 + 1] = valid ? sbox[1] : 0.f;
      outp[base * 4 + 2] = valid ? sbox[2] : 0.f;
      outp[base * 4 + 3] = valid ? sbox[3] : 0.f;
      outp[1600 + base] = valid ? best_v : 0.f;
      outp[2000 + base] = valid ? scls : -1.f;
    }
    float off_ = scls * (2.f * IMG_SIZE);
    float e0 = sbox[0] + off_, e1 = sbox[1] + off_, e2 = sbox[2] + off_, e3 = sbox[3] + off_;
    float a1 = (e2 - e0) * (e3 - e1);
#pragma unroll
    for (int j = 0; j < 20; ++j) {
      float o_ = cl[j] * (2.f * IMG_SIZE);
      float f0 = bx[j][0] + o_, f1 = bx[j][1] + o_, f2 = bx[j][2] + o_, f3 = bx[j][3] + o_;
      float xx1 = fmaxf(e0, f0), yy1 = fmaxf(e1, f1);
      float xx2 = fminf(e2, f2), yy2 = fminf(e3, f3);
      float inter = fmaxf(xx2 - xx1, 0.f) * fmaxf(yy2 - yy1, 0.f);
      float a2 = (f2 - f0) * (f3 - f1);
      float iou = inter / (a1 + a2 - inter + 1e-9f);
      if (iou > 0.6f) sc[j] = -1.f;
      if ((j * 256 + t) == best_g) sc[j] = -1.f;
    }
    __syncthreads();
  }
}

// ==================== host ====================
extern "C" void kernel_launch(void* const* d_in, const int* in_sizes, int n_in,
                              void* d_out, int out_size, void* d_ws, size_t ws_size,
                              hipStream_t stream)
{
  (void)in_sizes; (void)n_in; (void)out_size; (void)ws_size;
  const float* p3 = (const float*)d_in[0];
  const float* p4 = (const float*)d_in[1];
  const float* p5 = (const float*)d_in[2];
  const float* p6 = (const float*)d_in[3];
  const float* p7 = (const float*)d_in[4];
  const float* cls_tw  = (const float*)d_in[5];
  const float* cls_tb  = (const float*)d_in[6];
  const float* bbox_tw = (const float*)d_in[7];
  const float* bbox_tb = (const float*)d_in[8];
  const float* wcls    = (const float*)d_in[9];
  const float* bcls    = (const float*)d_in[10];
  const float* wbox    = (const float*)d_in[11];
  const float* bbox_b  = (const float*)d_in[12];
  const float* wctr    = (const float*)d_in[13];
  const float* bctr    = (const float*)d_in[14];
  const float* scales  = (const float*)d_in[15];
  float* out = (float*)d_out;

  // geometry (conv tiles 4 rows x 16 cols)
  Geo G;
  const int Hs[5] = {100, 50, 25, 13, 7};
  {
    int tpre = 0, ppre = 0, bpre = 0, phw = 0, hw = 0;
    for (int l = 0; l < 5; ++l) {
      int H = Hs[l], W = Hs[l];
      G.Ha[l] = H; G.Wa[l] = W; G.PWa[l] = W + 2; G.PHWa[l] = (H + 2) * (W + 2);
      G.TXa[l] = (W + 15) / 16;
      int TY = (H + 3) / 4;
      G.tp[l] = tpre;  tpre += G.TXa[l] * TY;
      G.pb[l] = ppre;  ppre += (H * W + 63) / 64;
      G.bb[l] = bpre;  bpre += (H * W + 255) / 256;
      G.phwOff[l] = phw; phw += G.PHWa[l];
      G.hwOff[l]  = hw;  hw  += H * W;
    }
    G.tp[5] = tpre; G.pb[5] = ppre; G.bb[5] = bpre;
  }
  const int nTiles = G.tp[5];   // 247
  const int nPrep  = G.pb[5];   // 211
  const int nBoxB  = G.bb[5];   // 55
  const int sumHW = 13343;
  const size_t scoreBytes  = (size_t)sumHW * 4 * 80 * 4;
  const size_t deltasBytes = (size_t)sumHW * 4 * 4 * 4;

  char* ws = (char*)d_ws;
  size_t off = 0;
  auto alloc = [&](size_t bytes) -> void* {
    off = (off + 255) & ~(size_t)255;
    void* p = ws + off; off += bytes; return p;
  };
  const size_t bufBytes = 2ull * PLANE * 2;   // one fp16 split-plane act buffer = 57.9 MB

  short* wt     = (short*)alloc((size_t)8 * 2 * 589824 * 2);   // 18.9 MB
  float* cbox   = (float*)alloc(4ull * 5000 * 4 * 4);
  float* csc    = (float*)alloc(4ull * 5000 * 4);
  float* ccls   = (float*)alloc(4ull * 5000 * 4);
  float* cgid   = (float*)alloc(4ull * 5000 * 4);
  unsigned* hist = (unsigned*)alloc(20ull * 2048 * 4);
  unsigned* thr  = (unsigned*)alloc(20ull * 8 * 4);
  short* A = (short*)alloc(bufBytes);
  short* B = (short*)alloc(bufBytes);
  float* score  = (float*)alloc(scoreBytes);
  float* deltas = (float*)alloc(deltasBytes);

  hipMemsetAsync(cbox, 0, 4ull * 5000 * 4 * 4, stream);
  hipMemsetAsync(csc,  0, 4ull * 5000 * 4, stream);
  hipMemsetAsync(ccls, 0, 4ull * 5000 * 4, stream);
  hipMemsetAsync(cgid, 0, 4ull * 5000 * 4, stream);
  hipMemsetAsync(thr,  0, 20ull * 8 * 4, stream);
  hipMemsetAsync(A, 0, bufBytes, stream);   // fp16 zero = 0x0000: borders stay exact 0
  hipMemsetAsync(B, 0, bufBytes, stream);

  wtrans_k<<<1024, 256, 0, stream>>>(cls_tw, bbox_tw, wt);

  const size_t LSTRIDE = 2ull * 589824;  // shorts per conv layer (2 planes)
  dim3 cg(nTiles, 2, 4);  // 1976 blocks/dispatch

  // cls tower: prep->A, A->B->A->B->A, head(A)
  prep_all_k<<<dim3(nPrep, 4), 256, 0, stream>>>(p3, p4, p5, p6, p7, A, G);
  conv_all_k<<<cg, 256, 0, stream>>>(A, A, wt + 0 * LSTRIDE, wt + 0 * LSTRIDE,
                                     cls_tb + 0 * 256, cls_tb + 0 * 256, B, B, G);
  conv_all_k<<<cg, 256, 0, stream>>>(B, B, wt + 1 * LSTRIDE, wt + 1 * LSTRIDE,
                                     cls_tb + 1 * 256, cls_tb + 1 * 256, A, A, G);
  conv_all_k<<<cg, 256, 0, stream>>>(A, A, wt + 2 * LSTRIDE, wt + 2 * LSTRIDE,
                                     cls_tb + 2 * 256, cls_tb + 2 * 256, B, B, G);
  conv_all_k<<<cg, 256, 0, stream>>>(B, B, wt + 3 * LSTRIDE, wt + 3 * LSTRIDE,
                                     cls_tb + 3 * 256, cls_tb + 3 * 256, A, A, G);
  cls_head_k<<<dim3(nPrep, 4), 256, 0, stream>>>(A, wcls, bcls, score, G);
  // bbox tower: re-prep->B, B->A->B->A->B, head(B)
  prep_all_k<<<dim3(nPrep, 4), 256, 0, stream>>>(p3, p4, p5, p6, p7, B, G);
  conv_all_k<<<cg, 256, 0, stream>>>(B, B, wt + 4 * LSTRIDE, wt + 4 * LSTRIDE,
                                     bbox_tb + 0 * 256, bbox_tb + 0 * 256, A, A, G);
  conv_all_k<<<cg, 256, 0, stream>>>(A, A, wt + 5 * LSTRIDE, wt + 5 * LSTRIDE,
                                     bbox_tb + 1 * 256, bbox_tb + 1 * 256, B, B, G);
  conv_all_k<<<cg, 256, 0, stream>>>(B, B, wt + 6 * LSTRIDE, wt + 6 * LSTRIDE,
                                     bbox_tb + 2 * 256, bbox_tb + 2 * 256, A, A, G);
  conv_all_k<<<cg, 256, 0, stream>>>(A, A, wt + 7 * LSTRIDE, wt + 7 * LSTRIDE,
                                     bbox_tb + 3 * 256, bbox_tb + 3 * 256, B, B, G);
  box_head_k<<<dim3(nBoxB, 4), 256, 0, stream>>>(B, wbox, bbox_b, wctr, bctr, scales,
                                                 score, deltas, G);

  // exact top-1000 per (level, image)
  const int hb = 196;
  for (int phase = 0; phase < 3; ++phase) {
    hipMemsetAsync(hist, 0, 20ull * 2048 * 4, stream);
    hist_k<<<dim3(hb, 20), 256, 0, stream>>>(score, thr, hist, phase, G);
    scan_k<<<20, 256, 0, stream>>>(hist, thr, phase);
  }
  select_k<<<dim3(hb, 20), 256, 0, stream>>>(score, deltas, thr, cbox, csc, ccls, cgid, G);

  nms_k<<<4, 256, 0, stream>>>(cbox, csc, ccls, cgid, out);
}